// Round 17
// baseline (497.521 us; speedup 1.0000x reference)
//
#include <hip/hip_runtime.h>
#include <hip/hip_bf16.h>

#define LEAKY 0.2f

typedef __attribute__((ext_vector_type(8))) short short8;
typedef __attribute__((ext_vector_type(4))) float f32x4;

// round-to-nearest-even float -> bf16 bits (finite inputs)
__device__ inline unsigned short f2b(float f) {
    unsigned u = __float_as_uint(f);
    u += 0x7FFFu + ((u >> 16) & 1u);
    return (unsigned short)(u >> 16);
}
__device__ inline float b2f(unsigned short s) {
    return __uint_as_float(((unsigned)s) << 16);
}

// ---------------- fused prep: features->bf16, W->Wt bf16, cnt=0 ----------------

__global__ void k_prep(const float* __restrict__ features, unsigned short* __restrict__ fconv,
                       int n4,
                       const float* __restrict__ W1, const float* __restrict__ W2,
                       const float* __restrict__ W3, unsigned short* __restrict__ Wt1,
                       unsigned short* __restrict__ Wt2, unsigned short* __restrict__ Wt3,
                       int* __restrict__ cnt, int N) {
    int idx = blockIdx.x * blockDim.x + threadIdx.x;
    if (idx < n4) {
        float4 v = *(const float4*)(features + idx * 4);
        ushort4 o;
        o.x = f2b(v.x); o.y = f2b(v.y); o.z = f2b(v.z); o.w = f2b(v.w);
        *(ushort4*)(fconv + idx * 4) = o;
        return;
    }
    int j = idx - n4;
    if (j < 32768) {                       // L1: K=128, M=256
        int m = j >> 7, k = j & 127;
        Wt1[j] = f2b(W1[(size_t)k * 256 + m]);
        return;
    }
    if (j < 98304) {                       // L2: K=256, M=256
        int jj = j - 32768;
        int m = jj >> 8, k = jj & 255;
        Wt2[jj] = f2b(W2[(size_t)k * 256 + m]);
        return;
    }
    if (j < 114688) {                      // L3: K=256, M=64
        int jj = j - 98304;
        int m = jj >> 8, k = jj & 255;
        Wt3[jj] = f2b(W3[(size_t)k * 64 + m]);
        return;
    }
    int z = j - 114688;
    if (z < N) cnt[z] = 0;
}

// ---------------- CSR build ----------------

__global__ void k_hist(const int* __restrict__ dst, int* __restrict__ cnt, int E, int N) {
    int e = blockIdx.x * blockDim.x + threadIdx.x;
    if (e >= E) return;
    int dn = dst[e];
    if ((unsigned)dn < (unsigned)N) atomicAdd(&cnt[dn], 1);
}

__global__ __launch_bounds__(256)
void k_bsum(const int* __restrict__ cnt, int* __restrict__ bsum, int N) {
    __shared__ int ws[4];
    int i = blockIdx.x * 256 + threadIdx.x;
    int lane = threadIdx.x & 63, wave = threadIdx.x >> 6;
    int v = (i < N) ? cnt[i] : 0;
    #pragma unroll
    for (int off = 32; off; off >>= 1) v += __shfl_down(v, off, 64);
    if (lane == 0) ws[wave] = v;
    __syncthreads();
    if (threadIdx.x == 0)
        bsum[blockIdx.x] = ws[0] + ws[1] + ws[2] + ws[3];
}

__global__ __launch_bounds__(256)
void k_scan_bsum(const int* __restrict__ bsum, int* __restrict__ boffs,
                 int* __restrict__ row_start_N, int NB) {
    __shared__ int ws[4];
    int tid = threadIdx.x, lane = tid & 63, wave = tid >> 6;
    int v = (tid < NB) ? bsum[tid] : 0;
    int x = v;
    #pragma unroll
    for (int off = 1; off < 64; off <<= 1) {
        int t = __shfl_up(x, off, 64);
        if (lane >= off) x += t;
    }
    if (lane == 63) ws[wave] = x;
    __syncthreads();
    if (tid == 0) {
        int c = 0;
        #pragma unroll
        for (int wv = 0; wv < 4; ++wv) { int t = ws[wv]; ws[wv] = c; c += t; }
    }
    __syncthreads();
    int excl = x - v + ws[wave];
    if (tid < NB) boffs[tid] = excl;
    if (tid == NB - 1) *row_start_N = excl + v;
}

__global__ __launch_bounds__(256)
void k_scan_write(const int* __restrict__ cnt, const int* __restrict__ boffs,
                  int* __restrict__ row_start, int* __restrict__ cursor, int N) {
    __shared__ int ws[4];
    int i = blockIdx.x * 256 + threadIdx.x;
    int tid = threadIdx.x, lane = tid & 63, wave = tid >> 6;
    int v = (i < N) ? cnt[i] : 0;
    int x = v;
    #pragma unroll
    for (int off = 1; off < 64; off <<= 1) {
        int t = __shfl_up(x, off, 64);
        if (lane >= off) x += t;
    }
    if (lane == 63) ws[wave] = x;
    __syncthreads();
    if (tid == 0) {
        int c = 0;
        #pragma unroll
        for (int wv = 0; wv < 4; ++wv) { int t = ws[wv]; ws[wv] = c; c += t; }
    }
    __syncthreads();
    int excl = x - v + ws[wave] + boffs[blockIdx.x];
    if (i < N) { row_start[i] = excl; cursor[i] = excl; }
}

__global__ void k_scatter(const int* __restrict__ src, const int* __restrict__ dst,
                          int* __restrict__ cursor, int* __restrict__ src_sorted,
                          int E, int N) {
    int e = blockIdx.x * blockDim.x + threadIdx.x;
    if (e >= E) return;
    int dn = dst[e];
    if ((unsigned)dn >= (unsigned)N) return;
    int pos = atomicAdd(&cursor[dn], 1);
    src_sorted[pos] = src[e];
}

// ---------------- MFMA GEMM (BN=128) + fused el/er epilogue ----------------

__global__ __launch_bounds__(256)
void k_gemm_mfma(const unsigned short* __restrict__ A, const unsigned short* __restrict__ Wt,
                 unsigned short* __restrict__ Cb, const float* __restrict__ al,
                 const float* __restrict__ ar, float* __restrict__ el,
                 float* __restrict__ er, int N, int K, int M) {
    constexpr int STR = 40;
    __shared__ unsigned short As[128 * STR];
    __shared__ unsigned short Bs[128 * STR];
    const int tid  = threadIdx.x;
    const int wave = tid >> 6;
    const int lane = tid & 63;
    const int row0 = blockIdx.y * 128;
    const int col0 = blockIdx.x * 128;
    const int wr = (wave >> 1) * 64;
    const int wc = (wave & 1) * 64;
    const int m16 = lane & 15;
    const int q   = lane >> 4;

    const int s_row = tid >> 1;
    const int s_off = (tid & 1) * 16;

    f32x4 acc[4][4] = {};

    for (int k0 = 0; k0 < K; k0 += 32) {
        {
            int gr = row0 + s_row;
            short8 z = {};
            short8 v0 = z, v1 = z;
            if (gr < N) {
                const unsigned short* ap = A + (size_t)gr * K + k0 + s_off;
                v0 = *(const short8*)ap;
                v1 = *(const short8*)(ap + 8);
            }
            *(short8*)&As[s_row * STR + s_off]     = v0;
            *(short8*)&As[s_row * STR + s_off + 8] = v1;
        }
        {
            const unsigned short* sp = Wt + (size_t)(col0 + s_row) * K + k0 + s_off;
            *(short8*)&Bs[s_row * STR + s_off]     = *(const short8*)sp;
            *(short8*)&Bs[s_row * STR + s_off + 8] = *(const short8*)(sp + 8);
        }
        __syncthreads();

        short8 afr[4], bfr[4];
        #pragma unroll
        for (int rg = 0; rg < 4; ++rg)
            afr[rg] = *(const short8*)&As[(wr + rg * 16 + m16) * STR + q * 8];
        #pragma unroll
        for (int cg = 0; cg < 4; ++cg)
            bfr[cg] = *(const short8*)&Bs[(wc + cg * 16 + m16) * STR + q * 8];
        #pragma unroll
        for (int rg = 0; rg < 4; ++rg)
            #pragma unroll
            for (int cg = 0; cg < 4; ++cg)
                acc[rg][cg] = __builtin_amdgcn_mfma_f32_16x16x32_bf16(
                    afr[rg], bfr[cg], acc[rg][cg], 0, 0, 0);
        __syncthreads();
    }

    const int H = M >> 6;
    const int h = (col0 + wc) >> 6;
    float alv[4], arv[4];
    #pragma unroll
    for (int cg = 0; cg < 4; ++cg) {
        alv[cg] = al[h * 64 + cg * 16 + m16];
        arv[cg] = ar[h * 64 + cg * 16 + m16];
    }

    #pragma unroll
    for (int rg = 0; rg < 4; ++rg) {
        #pragma unroll
        for (int r = 0; r < 4; ++r) {
            int gr = row0 + wr + rg * 16 + q * 4 + r;
            float pl = 0.f, pr = 0.f;
            #pragma unroll
            for (int cg = 0; cg < 4; ++cg) {
                pl = fmaf(acc[rg][cg][r], alv[cg], pl);
                pr = fmaf(acc[rg][cg][r], arv[cg], pr);
            }
            #pragma unroll
            for (int off = 1; off < 16; off <<= 1) {
                pl += __shfl_xor(pl, off, 64);
                pr += __shfl_xor(pr, off, 64);
            }
            if (gr < N) {
                unsigned short* bp = Cb + (size_t)gr * M + col0 + wc + m16;
                #pragma unroll
                for (int cg = 0; cg < 4; ++cg)
                    bp[cg * 16] = f2b(acc[rg][cg][r]);
                if (m16 == 0) {
                    el[gr * H + h] = pl;
                    er[gr * H + h] = pr;
                }
            }
        }
    }
}

// ---------------- MFMA GEMM (M=64): 256x64 tile + fused el/er (H=1) ----------

__global__ __launch_bounds__(256)
void k_gemm_mfma64(const unsigned short* __restrict__ A, const unsigned short* __restrict__ Wt,
                   unsigned short* __restrict__ Cb, const float* __restrict__ al,
                   const float* __restrict__ ar, float* __restrict__ el,
                   float* __restrict__ er, int N, int K) {
    constexpr int M = 64;
    constexpr int STR = 40;
    __shared__ unsigned short As[256 * STR];
    __shared__ unsigned short Bs[64 * STR];
    const int tid  = threadIdx.x;
    const int wave = tid >> 6;
    const int lane = tid & 63;
    const int row0 = blockIdx.x * 256;
    const int wr = wave * 64;
    const int m16 = lane & 15;
    const int q   = lane >> 4;

    const int s_row = tid >> 1;
    const int s_off = (tid & 1) * 16;
    const int b_row = tid >> 2;
    const int b_chk = (tid & 3) * 8;

    f32x4 acc[4][4] = {};

    for (int k0 = 0; k0 < K; k0 += 32) {
        #pragma unroll
        for (int p = 0; p < 2; ++p) {
            int r = s_row + p * 128;
            int gr = row0 + r;
            short8 z = {};
            short8 v0 = z, v1 = z;
            if (gr < N) {
                const unsigned short* ap = A + (size_t)gr * K + k0 + s_off;
                v0 = *(const short8*)ap;
                v1 = *(const short8*)(ap + 8);
            }
            *(short8*)&As[r * STR + s_off]     = v0;
            *(short8*)&As[r * STR + s_off + 8] = v1;
        }
        {
            const unsigned short* sp = Wt + (size_t)b_row * K + k0 + b_chk;
            *(short8*)&Bs[b_row * STR + b_chk] = *(const short8*)sp;
        }
        __syncthreads();

        short8 afr[4], bfr[4];
        #pragma unroll
        for (int rg = 0; rg < 4; ++rg)
            afr[rg] = *(const short8*)&As[(wr + rg * 16 + m16) * STR + q * 8];
        #pragma unroll
        for (int cg = 0; cg < 4; ++cg)
            bfr[cg] = *(const short8*)&Bs[(cg * 16 + m16) * STR + q * 8];
        #pragma unroll
        for (int rg = 0; rg < 4; ++rg)
            #pragma unroll
            for (int cg = 0; cg < 4; ++cg)
                acc[rg][cg] = __builtin_amdgcn_mfma_f32_16x16x32_bf16(
                    afr[rg], bfr[cg], acc[rg][cg], 0, 0, 0);
        __syncthreads();
    }

    float alv[4], arv[4];
    #pragma unroll
    for (int cg = 0; cg < 4; ++cg) {
        alv[cg] = al[cg * 16 + m16];
        arv[cg] = ar[cg * 16 + m16];
    }

    #pragma unroll
    for (int rg = 0; rg < 4; ++rg) {
        #pragma unroll
        for (int r = 0; r < 4; ++r) {
            int gr = row0 + wr + rg * 16 + q * 4 + r;
            float pl = 0.f, pr = 0.f;
            #pragma unroll
            for (int cg = 0; cg < 4; ++cg) {
                pl = fmaf(acc[rg][cg][r], alv[cg], pl);
                pr = fmaf(acc[rg][cg][r], arv[cg], pr);
            }
            #pragma unroll
            for (int off = 1; off < 16; off <<= 1) {
                pl += __shfl_xor(pl, off, 64);
                pr += __shfl_xor(pr, off, 64);
            }
            if (gr < N) {
                unsigned short* bp = Cb + (size_t)gr * M + m16;
                #pragma unroll
                for (int cg = 0; cg < 4; ++cg)
                    bp[cg * 16] = f2b(acc[rg][cg][r]);
                if (m16 == 0) {
                    el[gr] = pl;
                    er[gr] = pr;
                }
            }
        }
    }
}

// ---------------- fused softmax + aggregation ----------------
// Block = G nodes. Phase 1: wave-per-node softmax writes exp-weights to LDS
// (CAP slots per node-head; global spill for deg>CAP — never hit for this
// graph, Poisson(16) max-deg ~45, but correct if hit). Phase 2: agg gather
// reads weights from LDS. ldss = 1/sum per (node,head).

template<int H, int OUTBF>
__global__ __launch_bounds__(256)
void k_agg_fused(const int* __restrict__ row_start, const int* __restrict__ src_sorted,
                 const uint4* __restrict__ featp, const float* __restrict__ el,
                 const float* __restrict__ er, float* __restrict__ wspill,
                 const float* __restrict__ bias, void* __restrict__ outv,
                 int N, int E, int do_relu) {
    constexpr int M = H * 64;
    constexpr int P = M >> 3;          // threads per node (phase 2)
    constexpr int G = 256 / P;         // nodes per block
    constexpr int NW = G / 4;          // nodes per wave (phase 1)
    constexpr int CAP = 96;
    constexpr int LSTR = 97;           // bank-staggered stride
    __shared__ float ldsw[G * H * LSTR];
    __shared__ float ldss[G * H];
    const int tid  = threadIdx.x;
    const int wave = tid >> 6;
    const int lane = tid & 63;
    const int n0 = blockIdx.x * G;

    // ---- phase 1: softmax ----
    {
        constexpr int STRIDE = 64 / H;
        const int eo = lane / H;
        const int hh = lane % H;
        for (int k = 0; k < NW; ++k) {
            const int ln = wave * NW + k;
            const int n = n0 + ln;
            if (n >= N) break;
            const float erv = er[n * H + hh];
            const int b0 = row_start[n], b1 = row_start[n + 1];
            float* lw = &ldsw[(ln * H + hh) * LSTR];
            float mx = -INFINITY;
            for (int i = b0 + eo; i < b1; i += STRIDE) {
                float x = el[src_sorted[i] * H + hh] + erv;
                x = (x > 0.f) ? x : LEAKY * x;
                int j = i - b0;
                if (j < CAP) lw[j] = x;
                else wspill[(size_t)hh * E + i] = x;
                mx = fmaxf(mx, x);
            }
            #pragma unroll
            for (int off = H; off < 64; off <<= 1)
                mx = fmaxf(mx, __shfl_xor(mx, off, 64));
            float sum = 0.f;
            for (int i = b0 + eo; i < b1; i += STRIDE) {
                int j = i - b0;
                float x = (j < CAP) ? lw[j] : wspill[(size_t)hh * E + i];
                float e = __expf(x - mx);
                sum += e;
                if (j < CAP) lw[j] = e;
                else wspill[(size_t)hh * E + i] = e;
            }
            #pragma unroll
            for (int off = H; off < 64; off <<= 1)
                sum += __shfl_xor(sum, off, 64);
            if (lane < H) ldss[ln * H + lane] = 1.0f / fmaxf(sum, 1e-30f);
        }
    }
    __syncthreads();

    // ---- phase 2: aggregate ----
    const int grp = tid / P;
    const int t = tid - grp * P;
    const int n = n0 + grp;
    if (n >= N) return;
    const int d0 = t * 8;
    const int h = d0 >> 6;
    const float* lw  = &ldsw[(grp * H + h) * LSTR];
    const float* wsp = wspill + (size_t)h * E;

    float a[8] = {};
    const int b0 = row_start[n], b1 = row_start[n + 1];
    int i = b0;
    for (; i + 8 <= b1; i += 8) {
        int ss[8]; float wv[8]; uint4 pv[8];
        #pragma unroll
        for (int j = 0; j < 8; ++j) ss[j] = src_sorted[i + j];
        #pragma unroll
        for (int j = 0; j < 8; ++j) {
            int jj = i + j - b0;
            wv[j] = (jj < CAP) ? lw[jj] : wsp[i + j];
        }
        #pragma unroll
        for (int j = 0; j < 8; ++j) pv[j] = featp[(size_t)ss[j] * P + t];
        #pragma unroll
        for (int j = 0; j < 8; ++j) {
            a[0] = fmaf(__uint_as_float(pv[j].x << 16),         wv[j], a[0]);
            a[1] = fmaf(__uint_as_float(pv[j].x & 0xFFFF0000u), wv[j], a[1]);
            a[2] = fmaf(__uint_as_float(pv[j].y << 16),         wv[j], a[2]);
            a[3] = fmaf(__uint_as_float(pv[j].y & 0xFFFF0000u), wv[j], a[3]);
            a[4] = fmaf(__uint_as_float(pv[j].z << 16),         wv[j], a[4]);
            a[5] = fmaf(__uint_as_float(pv[j].z & 0xFFFF0000u), wv[j], a[5]);
            a[6] = fmaf(__uint_as_float(pv[j].w << 16),         wv[j], a[6]);
            a[7] = fmaf(__uint_as_float(pv[j].w & 0xFFFF0000u), wv[j], a[7]);
        }
    }
    for (; i < b1; ++i) {
        int jj = i - b0;
        float wv = (jj < CAP) ? lw[jj] : wsp[i];
        uint4 pv = featp[(size_t)src_sorted[i] * P + t];
        a[0] = fmaf(__uint_as_float(pv.x << 16),         wv, a[0]);
        a[1] = fmaf(__uint_as_float(pv.x & 0xFFFF0000u), wv, a[1]);
        a[2] = fmaf(__uint_as_float(pv.y << 16),         wv, a[2]);
        a[3] = fmaf(__uint_as_float(pv.y & 0xFFFF0000u), wv, a[3]);
        a[4] = fmaf(__uint_as_float(pv.z << 16),         wv, a[4]);
        a[5] = fmaf(__uint_as_float(pv.z & 0xFFFF0000u), wv, a[5]);
        a[6] = fmaf(__uint_as_float(pv.w << 16),         wv, a[6]);
        a[7] = fmaf(__uint_as_float(pv.w & 0xFFFF0000u), wv, a[7]);
    }
    float rs = ldss[grp * H + h];
    float4 bv0 = *(const float4*)(bias + d0);
    float4 bv1 = *(const float4*)(bias + d0 + 4);
    a[0] = fmaf(a[0], rs, bv0.x); a[1] = fmaf(a[1], rs, bv0.y);
    a[2] = fmaf(a[2], rs, bv0.z); a[3] = fmaf(a[3], rs, bv0.w);
    a[4] = fmaf(a[4], rs, bv1.x); a[5] = fmaf(a[5], rs, bv1.y);
    a[6] = fmaf(a[6], rs, bv1.z); a[7] = fmaf(a[7], rs, bv1.w);
    if (do_relu) {
        #pragma unroll
        for (int j = 0; j < 8; ++j) a[j] = fmaxf(a[j], 0.f);
    }
    if (OUTBF) {
        uint4 o;
        o.x = (unsigned)f2b(a[0]) | ((unsigned)f2b(a[1]) << 16);
        o.y = (unsigned)f2b(a[2]) | ((unsigned)f2b(a[3]) << 16);
        o.z = (unsigned)f2b(a[4]) | ((unsigned)f2b(a[5]) << 16);
        o.w = (unsigned)f2b(a[6]) | ((unsigned)f2b(a[7]) << 16);
        *(uint4*)((unsigned short*)outv + (size_t)n * M + d0) = o;
    } else {
        *(float4*)((float*)outv + (size_t)n * M + d0)     = make_float4(a[0], a[1], a[2], a[3]);
        *(float4*)((float*)outv + (size_t)n * M + d0 + 4) = make_float4(a[4], a[5], a[6], a[7]);
    }
}

// ---------------- host side ----------------

static void run_layer(const unsigned short* A, int K, const unsigned short* Wt,
                      const float* al_, const float* ar_, const float* b_, int H,
                      unsigned short* featb, void* rstOut, bool outBf,
                      float* el, float* er, float* wspill,
                      const int* row_start, const int* src_sorted,
                      int N, int E, bool do_relu, hipStream_t stream) {
    const int M = H * 64;
    if (M % 128 == 0) {
        dim3 gg(M / 128, (N + 127) / 128);
        k_gemm_mfma<<<gg, 256, 0, stream>>>(A, Wt, featb, al_, ar_, el, er, N, K, M);
    } else {
        k_gemm_mfma64<<<(N + 255) / 256, 256, 0, stream>>>(A, Wt, featb, al_, ar_, el, er, N, K);
    }

    int G = 256 / (M / 8);
    int grid = (N + G - 1) / G;
    int dr = do_relu ? 1 : 0;
    if (H == 4) {
        if (outBf)
            k_agg_fused<4, 1><<<grid, 256, 0, stream>>>(row_start, src_sorted,
                (const uint4*)featb, el, er, wspill, b_, rstOut, N, E, dr);
        else
            k_agg_fused<4, 0><<<grid, 256, 0, stream>>>(row_start, src_sorted,
                (const uint4*)featb, el, er, wspill, b_, rstOut, N, E, dr);
    } else {
        if (outBf)
            k_agg_fused<1, 1><<<grid, 256, 0, stream>>>(row_start, src_sorted,
                (const uint4*)featb, el, er, wspill, b_, rstOut, N, E, dr);
        else
            k_agg_fused<1, 0><<<grid, 256, 0, stream>>>(row_start, src_sorted,
                (const uint4*)featb, el, er, wspill, b_, rstOut, N, E, dr);
    }
}

extern "C" void kernel_launch(void* const* d_in, const int* in_sizes, int n_in,
                              void* d_out, int out_size, void* d_ws, size_t ws_size,
                              hipStream_t stream) {
    const float* features = (const float*)d_in[0];
    const int*   src = (const int*)d_in[1];
    const int*   dst = (const int*)d_in[2];
    const float* W1  = (const float*)d_in[3];
    const float* al1 = (const float*)d_in[4];
    const float* ar1 = (const float*)d_in[5];
    const float* b1  = (const float*)d_in[6];
    const float* W2  = (const float*)d_in[7];
    const float* al2 = (const float*)d_in[8];
    const float* ar2 = (const float*)d_in[9];
    const float* b2  = (const float*)d_in[10];
    const float* W3  = (const float*)d_in[11];
    const float* al3 = (const float*)d_in[12];
    const float* ar3 = (const float*)d_in[13];
    const float* b3  = (const float*)d_in[14];

    const int N = in_sizes[0] / 128;   // 50000
    const int E = in_sizes[1];         // 800000
    const int NB = (N + 255) / 256;    // scan blocks
    const int n4 = N * 128 / 4;        // convert chunks

    float* ws   = (float*)d_ws;
    float* el   = ws;                        // [N,4]
    float* er   = el + (size_t)N * 4;        // [N,4]
    float* wspill = er + (size_t)N * 4;      // [H][E] softmax spill (rarely used)
    int* cnt        = (int*)(wspill + (size_t)E * 4);  // [N]
    int* row_start  = cnt + N;                      // [N+1]
    int* cursor     = row_start + N + 1;            // [N]
    int* src_sorted = cursor + N;                   // [E]
    int* bsum       = src_sorted + E;               // [NB]
    int* boffs      = bsum + NB;                    // [NB]
    uintptr_t wp = (uintptr_t)(boffs + NB);
    wp = (wp + 15) & ~(uintptr_t)15;
    unsigned short* Wt1   = (unsigned short*)wp;       // [256*128]
    unsigned short* Wt2   = Wt1 + 32768;               // [256*256]
    unsigned short* Wt3   = Wt2 + 65536;               // [64*256]
    unsigned short* fconv = Wt3 + 16384;               // [N,128] bf16 features
    unsigned short* featb = fconv + (size_t)N * 128;   // [N,256] GEMM out
    unsigned short* rstb  = featb + (size_t)N * 256;   // [N,256] agg out (layers 1-2)

    // ---- fused prep: convert + weight transpose + cnt zero ----
    int prep_total = n4 + 114688 + N;
    k_prep<<<(prep_total + 255) / 256, 256, 0, stream>>>(features, fconv, n4,
                                                         W1, W2, W3, Wt1, Wt2, Wt3, cnt, N);

    // ---- build dst-CSR ----
    k_hist<<<(E + 255) / 256, 256, 0, stream>>>(dst, cnt, E, N);
    k_bsum<<<NB, 256, 0, stream>>>(cnt, bsum, N);
    k_scan_bsum<<<1, 256, 0, stream>>>(bsum, boffs, row_start + N, NB);
    k_scan_write<<<NB, 256, 0, stream>>>(cnt, boffs, row_start, cursor, N);
    k_scatter<<<(E + 255) / 256, 256, 0, stream>>>(src, dst, cursor, src_sorted, E, N);

    // layer 1: A=fconv[N,128] -> featb[N,256] (+el/er fused) -> rstb bf16 (+relu)
    run_layer(fconv, 128, Wt1, al1, ar1, b1, 4, featb, rstb, true,
              el, er, wspill, row_start, src_sorted, N, E, true, stream);
    // layer 2
    run_layer(rstb, 256, Wt2, al2, ar2, b2, 4, featb, rstb, true,
              el, er, wspill, row_start, src_sorted, N, E, true, stream);
    // layer 3: H=1 -> d_out fp32 (mean over 1 head = id)
    run_layer(rstb, 256, Wt3, al3, ar3, b3, 1, featb, d_out, false,
              el, er, wspill, row_start, src_sorted, N, E, false, stream);
}

// Round 18
// 490.151 us; speedup vs baseline: 1.0150x; 1.0150x over previous
//
#include <hip/hip_runtime.h>
#include <hip/hip_bf16.h>

#define LEAKY 0.2f

typedef __attribute__((ext_vector_type(8))) short short8;
typedef __attribute__((ext_vector_type(4))) float f32x4;

// round-to-nearest-even float -> bf16 bits (finite inputs)
__device__ inline unsigned short f2b(float f) {
    unsigned u = __float_as_uint(f);
    u += 0x7FFFu + ((u >> 16) & 1u);
    return (unsigned short)(u >> 16);
}
__device__ inline float b2f(unsigned short s) {
    return __uint_as_float(((unsigned)s) << 16);
}

// ---------------- fused prep: features->bf16, W->Wt bf16, cnt=0 ----------------

__global__ void k_prep(const float* __restrict__ features, unsigned short* __restrict__ fconv,
                       int n4,
                       const float* __restrict__ W1, const float* __restrict__ W2,
                       const float* __restrict__ W3, unsigned short* __restrict__ Wt1,
                       unsigned short* __restrict__ Wt2, unsigned short* __restrict__ Wt3,
                       int* __restrict__ cnt, int N) {
    int idx = blockIdx.x * blockDim.x + threadIdx.x;
    if (idx < n4) {
        float4 v = *(const float4*)(features + idx * 4);
        ushort4 o;
        o.x = f2b(v.x); o.y = f2b(v.y); o.z = f2b(v.z); o.w = f2b(v.w);
        *(ushort4*)(fconv + idx * 4) = o;
        return;
    }
    int j = idx - n4;
    if (j < 32768) {                       // L1: K=128, M=256
        int m = j >> 7, k = j & 127;
        Wt1[j] = f2b(W1[(size_t)k * 256 + m]);
        return;
    }
    if (j < 98304) {                       // L2: K=256, M=256
        int jj = j - 32768;
        int m = jj >> 8, k = jj & 255;
        Wt2[jj] = f2b(W2[(size_t)k * 256 + m]);
        return;
    }
    if (j < 114688) {                      // L3: K=256, M=64
        int jj = j - 98304;
        int m = jj >> 8, k = jj & 255;
        Wt3[jj] = f2b(W3[(size_t)k * 64 + m]);
        return;
    }
    int z = j - 114688;
    if (z < N) cnt[z] = 0;
}

// ---------------- CSR build ----------------

__global__ void k_hist(const int* __restrict__ dst, int* __restrict__ cnt, int E, int N) {
    int e = blockIdx.x * blockDim.x + threadIdx.x;
    if (e >= E) return;
    int dn = dst[e];
    if ((unsigned)dn < (unsigned)N) atomicAdd(&cnt[dn], 1);
}

__global__ __launch_bounds__(256)
void k_bsum(const int* __restrict__ cnt, int* __restrict__ bsum, int N) {
    __shared__ int ws[4];
    int i = blockIdx.x * 256 + threadIdx.x;
    int lane = threadIdx.x & 63, wave = threadIdx.x >> 6;
    int v = (i < N) ? cnt[i] : 0;
    #pragma unroll
    for (int off = 32; off; off >>= 1) v += __shfl_down(v, off, 64);
    if (lane == 0) ws[wave] = v;
    __syncthreads();
    if (threadIdx.x == 0)
        bsum[blockIdx.x] = ws[0] + ws[1] + ws[2] + ws[3];
}

__global__ __launch_bounds__(256)
void k_scan_bsum(const int* __restrict__ bsum, int* __restrict__ boffs,
                 int* __restrict__ row_start_N, int NB) {
    __shared__ int ws[4];
    int tid = threadIdx.x, lane = tid & 63, wave = tid >> 6;
    int v = (tid < NB) ? bsum[tid] : 0;
    int x = v;
    #pragma unroll
    for (int off = 1; off < 64; off <<= 1) {
        int t = __shfl_up(x, off, 64);
        if (lane >= off) x += t;
    }
    if (lane == 63) ws[wave] = x;
    __syncthreads();
    if (tid == 0) {
        int c = 0;
        #pragma unroll
        for (int wv = 0; wv < 4; ++wv) { int t = ws[wv]; ws[wv] = c; c += t; }
    }
    __syncthreads();
    int excl = x - v + ws[wave];
    if (tid < NB) boffs[tid] = excl;
    if (tid == NB - 1) *row_start_N = excl + v;
}

__global__ __launch_bounds__(256)
void k_scan_write(const int* __restrict__ cnt, const int* __restrict__ boffs,
                  int* __restrict__ row_start, int* __restrict__ cursor, int N) {
    __shared__ int ws[4];
    int i = blockIdx.x * 256 + threadIdx.x;
    int tid = threadIdx.x, lane = tid & 63, wave = tid >> 6;
    int v = (i < N) ? cnt[i] : 0;
    int x = v;
    #pragma unroll
    for (int off = 1; off < 64; off <<= 1) {
        int t = __shfl_up(x, off, 64);
        if (lane >= off) x += t;
    }
    if (lane == 63) ws[wave] = x;
    __syncthreads();
    if (tid == 0) {
        int c = 0;
        #pragma unroll
        for (int wv = 0; wv < 4; ++wv) { int t = ws[wv]; ws[wv] = c; c += t; }
    }
    __syncthreads();
    int excl = x - v + ws[wave] + boffs[blockIdx.x];
    if (i < N) { row_start[i] = excl; cursor[i] = excl; }
}

__global__ void k_scatter(const int* __restrict__ src, const int* __restrict__ dst,
                          int* __restrict__ cursor, int* __restrict__ src_sorted,
                          int E, int N) {
    int e = blockIdx.x * blockDim.x + threadIdx.x;
    if (e >= E) return;
    int dn = dst[e];
    if ((unsigned)dn >= (unsigned)N) return;
    int pos = atomicAdd(&cursor[dn], 1);
    src_sorted[pos] = src[e];
}

// ---------------- MFMA GEMM (BN=128) + fused el/er epilogue ----------------

__global__ __launch_bounds__(256)
void k_gemm_mfma(const unsigned short* __restrict__ A, const unsigned short* __restrict__ Wt,
                 unsigned short* __restrict__ Cb, const float* __restrict__ al,
                 const float* __restrict__ ar, float* __restrict__ el,
                 float* __restrict__ er, int N, int K, int M) {
    constexpr int STR = 40;
    __shared__ unsigned short As[128 * STR];
    __shared__ unsigned short Bs[128 * STR];
    const int tid  = threadIdx.x;
    const int wave = tid >> 6;
    const int lane = tid & 63;
    const int row0 = blockIdx.y * 128;
    const int col0 = blockIdx.x * 128;
    const int wr = (wave >> 1) * 64;
    const int wc = (wave & 1) * 64;
    const int m16 = lane & 15;
    const int q   = lane >> 4;

    const int s_row = tid >> 1;
    const int s_off = (tid & 1) * 16;

    f32x4 acc[4][4] = {};

    for (int k0 = 0; k0 < K; k0 += 32) {
        {
            int gr = row0 + s_row;
            short8 z = {};
            short8 v0 = z, v1 = z;
            if (gr < N) {
                const unsigned short* ap = A + (size_t)gr * K + k0 + s_off;
                v0 = *(const short8*)ap;
                v1 = *(const short8*)(ap + 8);
            }
            *(short8*)&As[s_row * STR + s_off]     = v0;
            *(short8*)&As[s_row * STR + s_off + 8] = v1;
        }
        {
            const unsigned short* sp = Wt + (size_t)(col0 + s_row) * K + k0 + s_off;
            *(short8*)&Bs[s_row * STR + s_off]     = *(const short8*)sp;
            *(short8*)&Bs[s_row * STR + s_off + 8] = *(const short8*)(sp + 8);
        }
        __syncthreads();

        short8 afr[4], bfr[4];
        #pragma unroll
        for (int rg = 0; rg < 4; ++rg)
            afr[rg] = *(const short8*)&As[(wr + rg * 16 + m16) * STR + q * 8];
        #pragma unroll
        for (int cg = 0; cg < 4; ++cg)
            bfr[cg] = *(const short8*)&Bs[(wc + cg * 16 + m16) * STR + q * 8];
        #pragma unroll
        for (int rg = 0; rg < 4; ++rg)
            #pragma unroll
            for (int cg = 0; cg < 4; ++cg)
                acc[rg][cg] = __builtin_amdgcn_mfma_f32_16x16x32_bf16(
                    afr[rg], bfr[cg], acc[rg][cg], 0, 0, 0);
        __syncthreads();
    }

    const int H = M >> 6;
    const int h = (col0 + wc) >> 6;
    float alv[4], arv[4];
    #pragma unroll
    for (int cg = 0; cg < 4; ++cg) {
        alv[cg] = al[h * 64 + cg * 16 + m16];
        arv[cg] = ar[h * 64 + cg * 16 + m16];
    }

    #pragma unroll
    for (int rg = 0; rg < 4; ++rg) {
        #pragma unroll
        for (int r = 0; r < 4; ++r) {
            int gr = row0 + wr + rg * 16 + q * 4 + r;
            float pl = 0.f, pr = 0.f;
            #pragma unroll
            for (int cg = 0; cg < 4; ++cg) {
                pl = fmaf(acc[rg][cg][r], alv[cg], pl);
                pr = fmaf(acc[rg][cg][r], arv[cg], pr);
            }
            #pragma unroll
            for (int off = 1; off < 16; off <<= 1) {
                pl += __shfl_xor(pl, off, 64);
                pr += __shfl_xor(pr, off, 64);
            }
            if (gr < N) {
                unsigned short* bp = Cb + (size_t)gr * M + col0 + wc + m16;
                #pragma unroll
                for (int cg = 0; cg < 4; ++cg)
                    bp[cg * 16] = f2b(acc[rg][cg][r]);
                if (m16 == 0) {
                    el[gr * H + h] = pl;
                    er[gr * H + h] = pr;
                }
            }
        }
    }
}

// ---------------- MFMA GEMM (M=64): 256x64 tile + fused el/er (H=1) ----------

__global__ __launch_bounds__(256)
void k_gemm_mfma64(const unsigned short* __restrict__ A, const unsigned short* __restrict__ Wt,
                   unsigned short* __restrict__ Cb, const float* __restrict__ al,
                   const float* __restrict__ ar, float* __restrict__ el,
                   float* __restrict__ er, int N, int K) {
    constexpr int M = 64;
    constexpr int STR = 40;
    __shared__ unsigned short As[256 * STR];
    __shared__ unsigned short Bs[64 * STR];
    const int tid  = threadIdx.x;
    const int wave = tid >> 6;
    const int lane = tid & 63;
    const int row0 = blockIdx.x * 256;
    const int wr = wave * 64;
    const int m16 = lane & 15;
    const int q   = lane >> 4;

    const int s_row = tid >> 1;
    const int s_off = (tid & 1) * 16;
    const int b_row = tid >> 2;
    const int b_chk = (tid & 3) * 8;

    f32x4 acc[4][4] = {};

    for (int k0 = 0; k0 < K; k0 += 32) {
        #pragma unroll
        for (int p = 0; p < 2; ++p) {
            int r = s_row + p * 128;
            int gr = row0 + r;
            short8 z = {};
            short8 v0 = z, v1 = z;
            if (gr < N) {
                const unsigned short* ap = A + (size_t)gr * K + k0 + s_off;
                v0 = *(const short8*)ap;
                v1 = *(const short8*)(ap + 8);
            }
            *(short8*)&As[r * STR + s_off]     = v0;
            *(short8*)&As[r * STR + s_off + 8] = v1;
        }
        {
            const unsigned short* sp = Wt + (size_t)b_row * K + k0 + b_chk;
            *(short8*)&Bs[b_row * STR + b_chk] = *(const short8*)sp;
        }
        __syncthreads();

        short8 afr[4], bfr[4];
        #pragma unroll
        for (int rg = 0; rg < 4; ++rg)
            afr[rg] = *(const short8*)&As[(wr + rg * 16 + m16) * STR + q * 8];
        #pragma unroll
        for (int cg = 0; cg < 4; ++cg)
            bfr[cg] = *(const short8*)&Bs[(cg * 16 + m16) * STR + q * 8];
        #pragma unroll
        for (int rg = 0; rg < 4; ++rg)
            #pragma unroll
            for (int cg = 0; cg < 4; ++cg)
                acc[rg][cg] = __builtin_amdgcn_mfma_f32_16x16x32_bf16(
                    afr[rg], bfr[cg], acc[rg][cg], 0, 0, 0);
        __syncthreads();
    }

    float alv[4], arv[4];
    #pragma unroll
    for (int cg = 0; cg < 4; ++cg) {
        alv[cg] = al[cg * 16 + m16];
        arv[cg] = ar[cg * 16 + m16];
    }

    #pragma unroll
    for (int rg = 0; rg < 4; ++rg) {
        #pragma unroll
        for (int r = 0; r < 4; ++r) {
            int gr = row0 + wr + rg * 16 + q * 4 + r;
            float pl = 0.f, pr = 0.f;
            #pragma unroll
            for (int cg = 0; cg < 4; ++cg) {
                pl = fmaf(acc[rg][cg][r], alv[cg], pl);
                pr = fmaf(acc[rg][cg][r], arv[cg], pr);
            }
            #pragma unroll
            for (int off = 1; off < 16; off <<= 1) {
                pl += __shfl_xor(pl, off, 64);
                pr += __shfl_xor(pr, off, 64);
            }
            if (gr < N) {
                unsigned short* bp = Cb + (size_t)gr * M + m16;
                #pragma unroll
                for (int cg = 0; cg < 4; ++cg)
                    bp[cg * 16] = f2b(acc[rg][cg][r]);
                if (m16 == 0) {
                    el[gr] = pl;
                    er[gr] = pr;
                }
            }
        }
    }
}

// ---------------- attention pieces (CSR, atomic-free) ----------------

// softmax per node: one wave per node. Pass 1 stores leaky-x in fp32 w[h*E+i],
// pass 2 exps and writes BF16 weights wb[h*E+i] (read by agg); s = 1/sum.
template<int H>
__global__ __launch_bounds__(256)
void k_node_msw(const int* __restrict__ row_start, const int* __restrict__ src_sorted,
                const float* __restrict__ el, const float* __restrict__ er,
                float* __restrict__ w, unsigned short* __restrict__ wb,
                float* __restrict__ s, int N, int E) {
    constexpr int STRIDE = 64 / H;
    const int n = blockIdx.x * 4 + (threadIdx.x >> 6);
    if (n >= N) return;
    const int lane = threadIdx.x & 63;
    const int eo = lane / H;
    const int h  = lane % H;
    float erv = er[n * H + h];
    int b0 = row_start[n], b1 = row_start[n + 1];
    float mx = -INFINITY;
    for (int i = b0 + eo; i < b1; i += STRIDE) {
        float x = el[src_sorted[i] * H + h] + erv;
        x = (x > 0.f) ? x : LEAKY * x;
        w[(size_t)h * E + i] = x;
        mx = fmaxf(mx, x);
    }
    #pragma unroll
    for (int off = H; off < 64; off <<= 1)
        mx = fmaxf(mx, __shfl_xor(mx, off, 64));
    float sum = 0.f;
    for (int i = b0 + eo; i < b1; i += STRIDE) {
        float e = __expf(w[(size_t)h * E + i] - mx);
        sum += e;
        wb[(size_t)h * E + i] = f2b(e);
    }
    #pragma unroll
    for (int off = H; off < 64; off <<= 1)
        sum += __shfl_xor(sum, off, 64);
    if (lane < H) s[n * H + lane] = 1.0f / fmaxf(sum, 1e-30f);
}

// Aggregation, packed bf16 octets (uint4 = 8 bf16/edge/thread), depth-8;
// weights read as bf16 (broadcast within node-group), 1/sum+bias epilogue.
template<int OUTBF>
__global__ __launch_bounds__(256)
void k_agg_b(const int* __restrict__ row_start, const int* __restrict__ src_sorted,
             const uint4* __restrict__ featp, const unsigned short* __restrict__ wb,
             const float* __restrict__ s, const float* __restrict__ bias,
             void* __restrict__ outv, int H, int N, int E, int do_relu) {
    const int M = H * 64;
    const int P = M >> 3;
    const int G = 256 / P;
    const int grp = threadIdx.x / P;
    const int t = threadIdx.x - grp * P;
    const int n = blockIdx.x * G + grp;
    if (n >= N) return;
    const int d0 = t * 8;
    const int h = d0 >> 6;
    const unsigned short* wh = wb + (size_t)h * E;

    float a[8] = {};
    int b0 = row_start[n], b1 = row_start[n + 1];
    int i = b0;
    for (; i + 8 <= b1; i += 8) {
        int ss[8]; float wv[8]; uint4 pv[8];
        #pragma unroll
        for (int j = 0; j < 8; ++j) ss[j] = src_sorted[i + j];
        #pragma unroll
        for (int j = 0; j < 8; ++j) wv[j] = b2f(wh[i + j]);
        #pragma unroll
        for (int j = 0; j < 8; ++j) pv[j] = featp[(size_t)ss[j] * P + t];
        #pragma unroll
        for (int j = 0; j < 8; ++j) {
            a[0] = fmaf(__uint_as_float(pv[j].x << 16),         wv[j], a[0]);
            a[1] = fmaf(__uint_as_float(pv[j].x & 0xFFFF0000u), wv[j], a[1]);
            a[2] = fmaf(__uint_as_float(pv[j].y << 16),         wv[j], a[2]);
            a[3] = fmaf(__uint_as_float(pv[j].y & 0xFFFF0000u), wv[j], a[3]);
            a[4] = fmaf(__uint_as_float(pv[j].z << 16),         wv[j], a[4]);
            a[5] = fmaf(__uint_as_float(pv[j].z & 0xFFFF0000u), wv[j], a[5]);
            a[6] = fmaf(__uint_as_float(pv[j].w << 16),         wv[j], a[6]);
            a[7] = fmaf(__uint_as_float(pv[j].w & 0xFFFF0000u), wv[j], a[7]);
        }
    }
    for (; i + 4 <= b1; i += 4) {
        int ss[4]; float wv[4]; uint4 pv[4];
        #pragma unroll
        for (int j = 0; j < 4; ++j) ss[j] = src_sorted[i + j];
        #pragma unroll
        for (int j = 0; j < 4; ++j) wv[j] = b2f(wh[i + j]);
        #pragma unroll
        for (int j = 0; j < 4; ++j) pv[j] = featp[(size_t)ss[j] * P + t];
        #pragma unroll
        for (int j = 0; j < 4; ++j) {
            a[0] = fmaf(__uint_as_float(pv[j].x << 16),         wv[j], a[0]);
            a[1] = fmaf(__uint_as_float(pv[j].x & 0xFFFF0000u), wv[j], a[1]);
            a[2] = fmaf(__uint_as_float(pv[j].y << 16),         wv[j], a[2]);
            a[3] = fmaf(__uint_as_float(pv[j].y & 0xFFFF0000u), wv[j], a[3]);
            a[4] = fmaf(__uint_as_float(pv[j].z << 16),         wv[j], a[4]);
            a[5] = fmaf(__uint_as_float(pv[j].z & 0xFFFF0000u), wv[j], a[5]);
            a[6] = fmaf(__uint_as_float(pv[j].w << 16),         wv[j], a[6]);
            a[7] = fmaf(__uint_as_float(pv[j].w & 0xFFFF0000u), wv[j], a[7]);
        }
    }
    for (; i < b1; ++i) {
        uint4 pv = featp[(size_t)src_sorted[i] * P + t];
        float wv = b2f(wh[i]);
        a[0] = fmaf(__uint_as_float(pv.x << 16),         wv, a[0]);
        a[1] = fmaf(__uint_as_float(pv.x & 0xFFFF0000u), wv, a[1]);
        a[2] = fmaf(__uint_as_float(pv.y << 16),         wv, a[2]);
        a[3] = fmaf(__uint_as_float(pv.y & 0xFFFF0000u), wv, a[3]);
        a[4] = fmaf(__uint_as_float(pv.z << 16),         wv, a[4]);
        a[5] = fmaf(__uint_as_float(pv.z & 0xFFFF0000u), wv, a[5]);
        a[6] = fmaf(__uint_as_float(pv.w << 16),         wv, a[6]);
        a[7] = fmaf(__uint_as_float(pv.w & 0xFFFF0000u), wv, a[7]);
    }
    float rs = s[n * H + h];
    float4 bv0 = *(const float4*)(bias + d0);
    float4 bv1 = *(const float4*)(bias + d0 + 4);
    a[0] = fmaf(a[0], rs, bv0.x); a[1] = fmaf(a[1], rs, bv0.y);
    a[2] = fmaf(a[2], rs, bv0.z); a[3] = fmaf(a[3], rs, bv0.w);
    a[4] = fmaf(a[4], rs, bv1.x); a[5] = fmaf(a[5], rs, bv1.y);
    a[6] = fmaf(a[6], rs, bv1.z); a[7] = fmaf(a[7], rs, bv1.w);
    if (do_relu) {
        #pragma unroll
        for (int j = 0; j < 8; ++j) a[j] = fmaxf(a[j], 0.f);
    }
    if (OUTBF) {
        uint4 o;
        o.x = (unsigned)f2b(a[0]) | ((unsigned)f2b(a[1]) << 16);
        o.y = (unsigned)f2b(a[2]) | ((unsigned)f2b(a[3]) << 16);
        o.z = (unsigned)f2b(a[4]) | ((unsigned)f2b(a[5]) << 16);
        o.w = (unsigned)f2b(a[6]) | ((unsigned)f2b(a[7]) << 16);
        *(uint4*)((unsigned short*)outv + (size_t)n * M + d0) = o;
    } else {
        *(float4*)((float*)outv + (size_t)n * M + d0)     = make_float4(a[0], a[1], a[2], a[3]);
        *(float4*)((float*)outv + (size_t)n * M + d0 + 4) = make_float4(a[4], a[5], a[6], a[7]);
    }
}

// ---------------- host side ----------------

static void run_layer(const unsigned short* A, int K, const unsigned short* Wt,
                      const float* al_, const float* ar_, const float* b_, int H,
                      unsigned short* featb, void* rstOut, bool outBf,
                      float* el, float* er, float* w, unsigned short* wb, float* s,
                      const int* row_start, const int* src_sorted,
                      int N, int E, bool do_relu, hipStream_t stream) {
    const int M = H * 64;
    if (M % 128 == 0) {
        dim3 gg(M / 128, (N + 127) / 128);
        k_gemm_mfma<<<gg, 256, 0, stream>>>(A, Wt, featb, al_, ar_, el, er, N, K, M);
    } else {
        k_gemm_mfma64<<<(N + 255) / 256, 256, 0, stream>>>(A, Wt, featb, al_, ar_, el, er, N, K);
    }

    if (H == 4)
        k_node_msw<4><<<(N + 3) / 4, 256, 0, stream>>>(row_start, src_sorted, el, er, w, wb, s, N, E);
    else
        k_node_msw<1><<<(N + 3) / 4, 256, 0, stream>>>(row_start, src_sorted, el, er, w, wb, s, N, E);

    int G = 256 / (M / 8);
    if (outBf)
        k_agg_b<1><<<(N + G - 1) / G, 256, 0, stream>>>(row_start, src_sorted,
                                                        (const uint4*)featb, wb, s,
                                                        b_, rstOut, H, N, E, do_relu ? 1 : 0);
    else
        k_agg_b<0><<<(N + G - 1) / G, 256, 0, stream>>>(row_start, src_sorted,
                                                        (const uint4*)featb, wb, s,
                                                        b_, rstOut, H, N, E, do_relu ? 1 : 0);
}

extern "C" void kernel_launch(void* const* d_in, const int* in_sizes, int n_in,
                              void* d_out, int out_size, void* d_ws, size_t ws_size,
                              hipStream_t stream) {
    const float* features = (const float*)d_in[0];
    const int*   src = (const int*)d_in[1];
    const int*   dst = (const int*)d_in[2];
    const float* W1  = (const float*)d_in[3];
    const float* al1 = (const float*)d_in[4];
    const float* ar1 = (const float*)d_in[5];
    const float* b1  = (const float*)d_in[6];
    const float* W2  = (const float*)d_in[7];
    const float* al2 = (const float*)d_in[8];
    const float* ar2 = (const float*)d_in[9];
    const float* b2  = (const float*)d_in[10];
    const float* W3  = (const float*)d_in[11];
    const float* al3 = (const float*)d_in[12];
    const float* ar3 = (const float*)d_in[13];
    const float* b3  = (const float*)d_in[14];

    const int N = in_sizes[0] / 128;   // 50000
    const int E = in_sizes[1];         // 800000
    const int NB = (N + 255) / 256;    // scan blocks
    const int n4 = N * 128 / 4;        // convert chunks

    float* ws   = (float*)d_ws;
    float* el   = ws;                        // [N,4]
    float* er   = el + (size_t)N * 4;        // [N,4]
    float* s    = er + (size_t)N * 4;        // [N,4]
    float* w    = s  + (size_t)N * 4;        // [H][E] fp32 logits (h-major)
    unsigned short* wb = (unsigned short*)(w + (size_t)E * 4);  // [H][E] bf16 exp-weights
    int* cnt        = (int*)(wb + (size_t)E * 4);  // [N]
    int* row_start  = cnt + N;                      // [N+1]
    int* cursor     = row_start + N + 1;            // [N]
    int* src_sorted = cursor + N;                   // [E]
    int* bsum       = src_sorted + E;               // [NB]
    int* boffs      = bsum + NB;                    // [NB]
    uintptr_t wp = (uintptr_t)(boffs + NB);
    wp = (wp + 15) & ~(uintptr_t)15;
    unsigned short* Wt1   = (unsigned short*)wp;       // [256*128]
    unsigned short* Wt2   = Wt1 + 32768;               // [256*256]
    unsigned short* Wt3   = Wt2 + 65536;               // [64*256]
    unsigned short* fconv = Wt3 + 16384;               // [N,128] bf16 features
    unsigned short* featb = fconv + (size_t)N * 128;   // [N,256] GEMM out
    unsigned short* rstb  = featb + (size_t)N * 256;   // [N,256] agg out (layers 1-2)

    // ---- fused prep: convert + weight transpose + cnt zero ----
    int prep_total = n4 + 114688 + N;
    k_prep<<<(prep_total + 255) / 256, 256, 0, stream>>>(features, fconv, n4,
                                                         W1, W2, W3, Wt1, Wt2, Wt3, cnt, N);

    // ---- build dst-CSR ----
    k_hist<<<(E + 255) / 256, 256, 0, stream>>>(dst, cnt, E, N);
    k_bsum<<<NB, 256, 0, stream>>>(cnt, bsum, N);
    k_scan_bsum<<<1, 256, 0, stream>>>(bsum, boffs, row_start + N, NB);
    k_scan_write<<<NB, 256, 0, stream>>>(cnt, boffs, row_start, cursor, N);
    k_scatter<<<(E + 255) / 256, 256, 0, stream>>>(src, dst, cursor, src_sorted, E, N);

    // layer 1: A=fconv[N,128] -> featb[N,256] (+el/er fused) -> rstb bf16 (+relu)
    run_layer(fconv, 128, Wt1, al1, ar1, b1, 4, featb, rstb, true,
              el, er, w, wb, s, row_start, src_sorted, N, E, true, stream);
    // layer 2
    run_layer(rstb, 256, Wt2, al2, ar2, b2, 4, featb, rstb, true,
              el, er, w, wb, s, row_start, src_sorted, N, E, true, stream);
    // layer 3: H=1 -> d_out fp32 (mean over 1 head = id)
    run_layer(rstb, 256, Wt3, al3, ar3, b3, 1, featb, d_out, false,
              el, er, w, wb, s, row_start, src_sorted, N, E, false, stream);
}

// Round 19
// 429.383 us; speedup vs baseline: 1.1587x; 1.1415x over previous
//
#include <hip/hip_runtime.h>
#include <hip/hip_bf16.h>

#define LEAKY 0.2f

typedef __attribute__((ext_vector_type(8))) short short8;
typedef __attribute__((ext_vector_type(4))) float f32x4;

// round-to-nearest-even float -> bf16 bits (finite inputs)
__device__ inline unsigned short f2b(float f) {
    unsigned u = __float_as_uint(f);
    u += 0x7FFFu + ((u >> 16) & 1u);
    return (unsigned short)(u >> 16);
}
__device__ inline float b2f(unsigned short s) {
    return __uint_as_float(((unsigned)s) << 16);
}

// ---------------- fused prep: features->bf16, W->Wt bf16, bcnt=0 ----------------

__global__ void k_prep(const float* __restrict__ features, unsigned short* __restrict__ fconv,
                       int n4,
                       const float* __restrict__ W1, const float* __restrict__ W2,
                       const float* __restrict__ W3, unsigned short* __restrict__ Wt1,
                       unsigned short* __restrict__ Wt2, unsigned short* __restrict__ Wt3,
                       int* __restrict__ bcnt) {
    int idx = blockIdx.x * blockDim.x + threadIdx.x;
    if (idx < n4) {
        float4 v = *(const float4*)(features + idx * 4);
        ushort4 o;
        o.x = f2b(v.x); o.y = f2b(v.y); o.z = f2b(v.z); o.w = f2b(v.w);
        *(ushort4*)(fconv + idx * 4) = o;
        return;
    }
    int j = idx - n4;
    if (j < 32768) {                       // L1: K=128, M=256
        int m = j >> 7, k = j & 127;
        Wt1[j] = f2b(W1[(size_t)k * 256 + m]);
        return;
    }
    if (j < 98304) {                       // L2: K=256, M=256
        int jj = j - 32768;
        int m = jj >> 8, k = jj & 255;
        Wt2[jj] = f2b(W2[(size_t)k * 256 + m]);
        return;
    }
    if (j < 114688) {                      // L3: K=256, M=64
        int jj = j - 98304;
        int m = jj >> 8, k = jj & 255;
        Wt3[jj] = f2b(W3[(size_t)k * 64 + m]);
        return;
    }
    int z = j - 114688;
    if (z < 256) bcnt[z] = 0;
}

// ---------------- bucketed CSR build ----------------
// bucket k = dst >> 8 (256 nodes/bucket). Avoids cross-XCD cache-line
// bouncing: per-bucket output regions are written by single blocks.

#define NEB 8192   // edges per binning block

// per-bucket histogram, LDS-aggregated
__global__ __launch_bounds__(256)
void k_bin_count(const int* __restrict__ dst, int* __restrict__ bcnt, int E, int N) {
    __shared__ int lc[256];
    const int tid = threadIdx.x;
    lc[tid] = 0;
    __syncthreads();
    const int b0 = blockIdx.x * NEB;
    const int cnt = min(NEB, E - b0);
    for (int j = 0; j < NEB / 256; ++j) {
        int idx = j * 256 + tid;
        if (idx < cnt) {
            int dn = dst[b0 + idx];
            if ((unsigned)dn < (unsigned)N) atomicAdd(&lc[dn >> 8], 1);
        }
    }
    __syncthreads();
    if (lc[tid] > 0) atomicAdd(&bcnt[tid], lc[tid]);
}

// single-block exclusive scan over B buckets; bbase[B]=E; bcur=bbase; row_start[N]=E
__global__ __launch_bounds__(256)
void k_bucket_scan(const int* __restrict__ bcnt, int* __restrict__ bbase,
                   int* __restrict__ bcur, int* __restrict__ row_start_N, int B, int E) {
    __shared__ int ws[4];
    const int tid = threadIdx.x, lane = tid & 63, wave = tid >> 6;
    int v = (tid < B) ? bcnt[tid] : 0;
    int x = v;
    #pragma unroll
    for (int off = 1; off < 64; off <<= 1) {
        int t = __shfl_up(x, off, 64);
        if (lane >= off) x += t;
    }
    if (lane == 63) ws[wave] = x;
    __syncthreads();
    if (tid == 0) {
        int c = 0;
        #pragma unroll
        for (int wv = 0; wv < 4; ++wv) { int t = ws[wv]; ws[wv] = c; c += t; }
    }
    __syncthreads();
    int excl = x - v + ws[wave];
    if (tid < B) { bbase[tid] = excl; bcur[tid] = excl; }
    if (tid == 0) { bbase[B] = E; *row_start_N = E; }
}

// bin edges into bucket-contiguous ebuf, run-coalesced writes.
// ebuf entry packs (dst&255)<<24 | e  (e < 2^24).
__global__ __launch_bounds__(256)
void k_bin_scatter(const int* __restrict__ dst, int* __restrict__ bcur,
                   int* __restrict__ ebuf, int E, int N) {
    __shared__ int lc[256], lofs[256], lcur[256], gres[256];
    __shared__ int stage_e[NEB];
    __shared__ unsigned short stage_d[NEB];
    __shared__ int ws[4];
    const int tid = threadIdx.x, lane = tid & 63, wave = tid >> 6;
    const int b0 = blockIdx.x * NEB;
    const int cnt = min(NEB, E - b0);
    lc[tid] = 0;
    __syncthreads();

    int dreg[NEB / 256];
    #pragma unroll
    for (int j = 0; j < NEB / 256; ++j) {
        int idx = j * 256 + tid;
        dreg[j] = -1;
        if (idx < cnt) {
            int dn = dst[b0 + idx];
            if ((unsigned)dn < (unsigned)N) {
                dreg[j] = dn;
                atomicAdd(&lc[dn >> 8], 1);
            }
        }
    }
    __syncthreads();
    // block scan of 256 counters
    {
        int v = lc[tid];
        int x = v;
        #pragma unroll
        for (int off = 1; off < 64; off <<= 1) {
            int t = __shfl_up(x, off, 64);
            if (lane >= off) x += t;
        }
        if (lane == 63) ws[wave] = x;
        __syncthreads();
        if (tid == 0) {
            int c = 0;
            #pragma unroll
            for (int wv = 0; wv < 4; ++wv) { int t = ws[wv]; ws[wv] = c; c += t; }
        }
        __syncthreads();
        int excl = x - v + ws[wave];
        lofs[tid] = excl;
        lcur[tid] = excl;
    }
    __syncthreads();
    // local bucket-sort into stage
    #pragma unroll
    for (int j = 0; j < NEB / 256; ++j) {
        int dn = dreg[j];
        if (dn >= 0) {
            int p = atomicAdd(&lcur[dn >> 8], 1);
            stage_e[p] = b0 + j * 256 + tid;
            stage_d[p] = (unsigned short)dn;
        }
    }
    __syncthreads();
    // reserve global runs
    if (lc[tid] > 0) gres[tid] = atomicAdd(&bcur[tid], lc[tid]);
    __syncthreads();
    // write runs out (coalesced within runs; single-writer lines)
    int total = lcur[255];
    for (int i = tid; i < total; i += 256) {
        int dn = stage_d[i];
        int k = dn >> 8;
        int dest = gres[k] + (i - lofs[k]);
        ebuf[dest] = ((dn & 255) << 24) | stage_e[i];
    }
}

// per bucket: derive row_start for its 256 nodes (no global hist needed)
// and write final src_sorted region (exclusive to this block).
__global__ __launch_bounds__(256)
void k_csr_build(const int* __restrict__ ebuf, const int* __restrict__ src,
                 const int* __restrict__ bbase, int* __restrict__ row_start,
                 int* __restrict__ src_sorted, int N) {
    __shared__ int lc[256], lofs[256], lcur[256];
    __shared__ int ws[4];
    const int tid = threadIdx.x, lane = tid & 63, wave = tid >> 6;
    const int k = blockIdx.x;
    const int base = k << 8;
    const int e0 = bbase[k];
    const int cnt = bbase[k + 1] - e0;
    lc[tid] = 0;
    __syncthreads();
    for (int i = tid; i < cnt; i += 256) {
        int rel = ((unsigned)ebuf[e0 + i]) >> 24;
        atomicAdd(&lc[rel], 1);
    }
    __syncthreads();
    {
        int v = lc[tid];
        int x = v;
        #pragma unroll
        for (int off = 1; off < 64; off <<= 1) {
            int t = __shfl_up(x, off, 64);
            if (lane >= off) x += t;
        }
        if (lane == 63) ws[wave] = x;
        __syncthreads();
        if (tid == 0) {
            int c = 0;
            #pragma unroll
            for (int wv = 0; wv < 4; ++wv) { int t = ws[wv]; ws[wv] = c; c += t; }
        }
        __syncthreads();
        int excl = x - v + ws[wave];
        lofs[tid] = excl;
        lcur[tid] = excl;
        int n = base + tid;
        if (n < N) row_start[n] = e0 + excl;
    }
    __syncthreads();
    for (int i = tid; i < cnt; i += 256) {
        int val = ebuf[e0 + i];
        int rel = ((unsigned)val) >> 24;
        int e = val & 0xFFFFFF;
        int p = atomicAdd(&lcur[rel], 1);
        src_sorted[e0 + p] = src[e];
    }
}

// ---------------- MFMA GEMM (BN=128) + fused el/er epilogue ----------------

__global__ __launch_bounds__(256)
void k_gemm_mfma(const unsigned short* __restrict__ A, const unsigned short* __restrict__ Wt,
                 unsigned short* __restrict__ Cb, const float* __restrict__ al,
                 const float* __restrict__ ar, float* __restrict__ el,
                 float* __restrict__ er, int N, int K, int M) {
    constexpr int STR = 40;
    __shared__ unsigned short As[128 * STR];
    __shared__ unsigned short Bs[128 * STR];
    const int tid  = threadIdx.x;
    const int wave = tid >> 6;
    const int lane = tid & 63;
    const int row0 = blockIdx.y * 128;
    const int col0 = blockIdx.x * 128;
    const int wr = (wave >> 1) * 64;
    const int wc = (wave & 1) * 64;
    const int m16 = lane & 15;
    const int q   = lane >> 4;

    const int s_row = tid >> 1;
    const int s_off = (tid & 1) * 16;

    f32x4 acc[4][4] = {};

    for (int k0 = 0; k0 < K; k0 += 32) {
        {
            int gr = row0 + s_row;
            short8 z = {};
            short8 v0 = z, v1 = z;
            if (gr < N) {
                const unsigned short* ap = A + (size_t)gr * K + k0 + s_off;
                v0 = *(const short8*)ap;
                v1 = *(const short8*)(ap + 8);
            }
            *(short8*)&As[s_row * STR + s_off]     = v0;
            *(short8*)&As[s_row * STR + s_off + 8] = v1;
        }
        {
            const unsigned short* sp = Wt + (size_t)(col0 + s_row) * K + k0 + s_off;
            *(short8*)&Bs[s_row * STR + s_off]     = *(const short8*)sp;
            *(short8*)&Bs[s_row * STR + s_off + 8] = *(const short8*)(sp + 8);
        }
        __syncthreads();

        short8 afr[4], bfr[4];
        #pragma unroll
        for (int rg = 0; rg < 4; ++rg)
            afr[rg] = *(const short8*)&As[(wr + rg * 16 + m16) * STR + q * 8];
        #pragma unroll
        for (int cg = 0; cg < 4; ++cg)
            bfr[cg] = *(const short8*)&Bs[(wc + cg * 16 + m16) * STR + q * 8];
        #pragma unroll
        for (int rg = 0; rg < 4; ++rg)
            #pragma unroll
            for (int cg = 0; cg < 4; ++cg)
                acc[rg][cg] = __builtin_amdgcn_mfma_f32_16x16x32_bf16(
                    afr[rg], bfr[cg], acc[rg][cg], 0, 0, 0);
        __syncthreads();
    }

    const int H = M >> 6;
    const int h = (col0 + wc) >> 6;
    float alv[4], arv[4];
    #pragma unroll
    for (int cg = 0; cg < 4; ++cg) {
        alv[cg] = al[h * 64 + cg * 16 + m16];
        arv[cg] = ar[h * 64 + cg * 16 + m16];
    }

    #pragma unroll
    for (int rg = 0; rg < 4; ++rg) {
        #pragma unroll
        for (int r = 0; r < 4; ++r) {
            int gr = row0 + wr + rg * 16 + q * 4 + r;
            float pl = 0.f, pr = 0.f;
            #pragma unroll
            for (int cg = 0; cg < 4; ++cg) {
                pl = fmaf(acc[rg][cg][r], alv[cg], pl);
                pr = fmaf(acc[rg][cg][r], arv[cg], pr);
            }
            #pragma unroll
            for (int off = 1; off < 16; off <<= 1) {
                pl += __shfl_xor(pl, off, 64);
                pr += __shfl_xor(pr, off, 64);
            }
            if (gr < N) {
                unsigned short* bp = Cb + (size_t)gr * M + col0 + wc + m16;
                #pragma unroll
                for (int cg = 0; cg < 4; ++cg)
                    bp[cg * 16] = f2b(acc[rg][cg][r]);
                if (m16 == 0) {
                    el[gr * H + h] = pl;
                    er[gr * H + h] = pr;
                }
            }
        }
    }
}

// ---------------- MFMA GEMM (M=64): 256x64 tile + fused el/er (H=1) ----------

__global__ __launch_bounds__(256)
void k_gemm_mfma64(const unsigned short* __restrict__ A, const unsigned short* __restrict__ Wt,
                   unsigned short* __restrict__ Cb, const float* __restrict__ al,
                   const float* __restrict__ ar, float* __restrict__ el,
                   float* __restrict__ er, int N, int K) {
    constexpr int M = 64;
    constexpr int STR = 40;
    __shared__ unsigned short As[256 * STR];
    __shared__ unsigned short Bs[64 * STR];
    const int tid  = threadIdx.x;
    const int wave = tid >> 6;
    const int lane = tid & 63;
    const int row0 = blockIdx.x * 256;
    const int wr = wave * 64;
    const int m16 = lane & 15;
    const int q   = lane >> 4;

    const int s_row = tid >> 1;
    const int s_off = (tid & 1) * 16;
    const int b_row = tid >> 2;
    const int b_chk = (tid & 3) * 8;

    f32x4 acc[4][4] = {};

    for (int k0 = 0; k0 < K; k0 += 32) {
        #pragma unroll
        for (int p = 0; p < 2; ++p) {
            int r = s_row + p * 128;
            int gr = row0 + r;
            short8 z = {};
            short8 v0 = z, v1 = z;
            if (gr < N) {
                const unsigned short* ap = A + (size_t)gr * K + k0 + s_off;
                v0 = *(const short8*)ap;
                v1 = *(const short8*)(ap + 8);
            }
            *(short8*)&As[r * STR + s_off]     = v0;
            *(short8*)&As[r * STR + s_off + 8] = v1;
        }
        {
            const unsigned short* sp = Wt + (size_t)b_row * K + k0 + b_chk;
            *(short8*)&Bs[b_row * STR + b_chk] = *(const short8*)sp;
        }
        __syncthreads();

        short8 afr[4], bfr[4];
        #pragma unroll
        for (int rg = 0; rg < 4; ++rg)
            afr[rg] = *(const short8*)&As[(wr + rg * 16 + m16) * STR + q * 8];
        #pragma unroll
        for (int cg = 0; cg < 4; ++cg)
            bfr[cg] = *(const short8*)&Bs[(cg * 16 + m16) * STR + q * 8];
        #pragma unroll
        for (int rg = 0; rg < 4; ++rg)
            #pragma unroll
            for (int cg = 0; cg < 4; ++cg)
                acc[rg][cg] = __builtin_amdgcn_mfma_f32_16x16x32_bf16(
                    afr[rg], bfr[cg], acc[rg][cg], 0, 0, 0);
        __syncthreads();
    }

    float alv[4], arv[4];
    #pragma unroll
    for (int cg = 0; cg < 4; ++cg) {
        alv[cg] = al[cg * 16 + m16];
        arv[cg] = ar[cg * 16 + m16];
    }

    #pragma unroll
    for (int rg = 0; rg < 4; ++rg) {
        #pragma unroll
        for (int r = 0; r < 4; ++r) {
            int gr = row0 + wr + rg * 16 + q * 4 + r;
            float pl = 0.f, pr = 0.f;
            #pragma unroll
            for (int cg = 0; cg < 4; ++cg) {
                pl = fmaf(acc[rg][cg][r], alv[cg], pl);
                pr = fmaf(acc[rg][cg][r], arv[cg], pr);
            }
            #pragma unroll
            for (int off = 1; off < 16; off <<= 1) {
                pl += __shfl_xor(pl, off, 64);
                pr += __shfl_xor(pr, off, 64);
            }
            if (gr < N) {
                unsigned short* bp = Cb + (size_t)gr * M + m16;
                #pragma unroll
                for (int cg = 0; cg < 4; ++cg)
                    bp[cg * 16] = f2b(acc[rg][cg][r]);
                if (m16 == 0) {
                    el[gr] = pl;
                    er[gr] = pr;
                }
            }
        }
    }
}

// ---------------- attention pieces (CSR, atomic-free) ----------------

// softmax per node: one wave per node; bf16 exp-weights wb[h*E+i]; s=1/sum
template<int H>
__global__ __launch_bounds__(256)
void k_node_msw(const int* __restrict__ row_start, const int* __restrict__ src_sorted,
                const float* __restrict__ el, const float* __restrict__ er,
                float* __restrict__ w, unsigned short* __restrict__ wb,
                float* __restrict__ s, int N, int E) {
    constexpr int STRIDE = 64 / H;
    const int n = blockIdx.x * 4 + (threadIdx.x >> 6);
    if (n >= N) return;
    const int lane = threadIdx.x & 63;
    const int eo = lane / H;
    const int h  = lane % H;
    float erv = er[n * H + h];
    int b0 = row_start[n], b1 = row_start[n + 1];
    float mx = -INFINITY;
    for (int i = b0 + eo; i < b1; i += STRIDE) {
        float x = el[src_sorted[i] * H + h] + erv;
        x = (x > 0.f) ? x : LEAKY * x;
        w[(size_t)h * E + i] = x;
        mx = fmaxf(mx, x);
    }
    #pragma unroll
    for (int off = H; off < 64; off <<= 1)
        mx = fmaxf(mx, __shfl_xor(mx, off, 64));
    float sum = 0.f;
    for (int i = b0 + eo; i < b1; i += STRIDE) {
        float e = __expf(w[(size_t)h * E + i] - mx);
        sum += e;
        wb[(size_t)h * E + i] = f2b(e);
    }
    #pragma unroll
    for (int off = H; off < 64; off <<= 1)
        sum += __shfl_xor(sum, off, 64);
    if (lane < H) s[n * H + lane] = 1.0f / fmaxf(sum, 1e-30f);
}

// Aggregation, packed bf16 octets (uint4 = 8 bf16/edge/thread), depth-8;
// bf16 weights, 1/sum+bias epilogue.
template<int OUTBF>
__global__ __launch_bounds__(256)
void k_agg_b(const int* __restrict__ row_start, const int* __restrict__ src_sorted,
             const uint4* __restrict__ featp, const unsigned short* __restrict__ wb,
             const float* __restrict__ s, const float* __restrict__ bias,
             void* __restrict__ outv, int H, int N, int E, int do_relu) {
    const int M = H * 64;
    const int P = M >> 3;
    const int G = 256 / P;
    const int grp = threadIdx.x / P;
    const int t = threadIdx.x - grp * P;
    const int n = blockIdx.x * G + grp;
    if (n >= N) return;
    const int d0 = t * 8;
    const int h = d0 >> 6;
    const unsigned short* wh = wb + (size_t)h * E;

    float a[8] = {};
    int b0 = row_start[n], b1 = row_start[n + 1];
    int i = b0;
    for (; i + 8 <= b1; i += 8) {
        int ss[8]; float wv[8]; uint4 pv[8];
        #pragma unroll
        for (int j = 0; j < 8; ++j) ss[j] = src_sorted[i + j];
        #pragma unroll
        for (int j = 0; j < 8; ++j) wv[j] = b2f(wh[i + j]);
        #pragma unroll
        for (int j = 0; j < 8; ++j) pv[j] = featp[(size_t)ss[j] * P + t];
        #pragma unroll
        for (int j = 0; j < 8; ++j) {
            a[0] = fmaf(__uint_as_float(pv[j].x << 16),         wv[j], a[0]);
            a[1] = fmaf(__uint_as_float(pv[j].x & 0xFFFF0000u), wv[j], a[1]);
            a[2] = fmaf(__uint_as_float(pv[j].y << 16),         wv[j], a[2]);
            a[3] = fmaf(__uint_as_float(pv[j].y & 0xFFFF0000u), wv[j], a[3]);
            a[4] = fmaf(__uint_as_float(pv[j].z << 16),         wv[j], a[4]);
            a[5] = fmaf(__uint_as_float(pv[j].z & 0xFFFF0000u), wv[j], a[5]);
            a[6] = fmaf(__uint_as_float(pv[j].w << 16),         wv[j], a[6]);
            a[7] = fmaf(__uint_as_float(pv[j].w & 0xFFFF0000u), wv[j], a[7]);
        }
    }
    for (; i + 4 <= b1; i += 4) {
        int ss[4]; float wv[4]; uint4 pv[4];
        #pragma unroll
        for (int j = 0; j < 4; ++j) ss[j] = src_sorted[i + j];
        #pragma unroll
        for (int j = 0; j < 4; ++j) wv[j] = b2f(wh[i + j]);
        #pragma unroll
        for (int j = 0; j < 4; ++j) pv[j] = featp[(size_t)ss[j] * P + t];
        #pragma unroll
        for (int j = 0; j < 4; ++j) {
            a[0] = fmaf(__uint_as_float(pv[j].x << 16),         wv[j], a[0]);
            a[1] = fmaf(__uint_as_float(pv[j].x & 0xFFFF0000u), wv[j], a[1]);
            a[2] = fmaf(__uint_as_float(pv[j].y << 16),         wv[j], a[2]);
            a[3] = fmaf(__uint_as_float(pv[j].y & 0xFFFF0000u), wv[j], a[3]);
            a[4] = fmaf(__uint_as_float(pv[j].z << 16),         wv[j], a[4]);
            a[5] = fmaf(__uint_as_float(pv[j].z & 0xFFFF0000u), wv[j], a[5]);
            a[6] = fmaf(__uint_as_float(pv[j].w << 16),         wv[j], a[6]);
            a[7] = fmaf(__uint_as_float(pv[j].w & 0xFFFF0000u), wv[j], a[7]);
        }
    }
    for (; i < b1; ++i) {
        uint4 pv = featp[(size_t)src_sorted[i] * P + t];
        float wv = b2f(wh[i]);
        a[0] = fmaf(__uint_as_float(pv.x << 16),         wv, a[0]);
        a[1] = fmaf(__uint_as_float(pv.x & 0xFFFF0000u), wv, a[1]);
        a[2] = fmaf(__uint_as_float(pv.y << 16),         wv, a[2]);
        a[3] = fmaf(__uint_as_float(pv.y & 0xFFFF0000u), wv, a[3]);
        a[4] = fmaf(__uint_as_float(pv.z << 16),         wv, a[4]);
        a[5] = fmaf(__uint_as_float(pv.z & 0xFFFF0000u), wv, a[5]);
        a[6] = fmaf(__uint_as_float(pv.w << 16),         wv, a[6]);
        a[7] = fmaf(__uint_as_float(pv.w & 0xFFFF0000u), wv, a[7]);
    }
    float rs = s[n * H + h];
    float4 bv0 = *(const float4*)(bias + d0);
    float4 bv1 = *(const float4*)(bias + d0 + 4);
    a[0] = fmaf(a[0], rs, bv0.x); a[1] = fmaf(a[1], rs, bv0.y);
    a[2] = fmaf(a[2], rs, bv0.z); a[3] = fmaf(a[3], rs, bv0.w);
    a[4] = fmaf(a[4], rs, bv1.x); a[5] = fmaf(a[5], rs, bv1.y);
    a[6] = fmaf(a[6], rs, bv1.z); a[7] = fmaf(a[7], rs, bv1.w);
    if (do_relu) {
        #pragma unroll
        for (int j = 0; j < 8; ++j) a[j] = fmaxf(a[j], 0.f);
    }
    if (OUTBF) {
        uint4 o;
        o.x = (unsigned)f2b(a[0]) | ((unsigned)f2b(a[1]) << 16);
        o.y = (unsigned)f2b(a[2]) | ((unsigned)f2b(a[3]) << 16);
        o.z = (unsigned)f2b(a[4]) | ((unsigned)f2b(a[5]) << 16);
        o.w = (unsigned)f2b(a[6]) | ((unsigned)f2b(a[7]) << 16);
        *(uint4*)((unsigned short*)outv + (size_t)n * M + d0) = o;
    } else {
        *(float4*)((float*)outv + (size_t)n * M + d0)     = make_float4(a[0], a[1], a[2], a[3]);
        *(float4*)((float*)outv + (size_t)n * M + d0 + 4) = make_float4(a[4], a[5], a[6], a[7]);
    }
}

// ---------------- host side ----------------

static void run_layer(const unsigned short* A, int K, const unsigned short* Wt,
                      const float* al_, const float* ar_, const float* b_, int H,
                      unsigned short* featb, void* rstOut, bool outBf,
                      float* el, float* er, float* w, unsigned short* wb, float* s,
                      const int* row_start, const int* src_sorted,
                      int N, int E, bool do_relu, hipStream_t stream) {
    const int M = H * 64;
    if (M % 128 == 0) {
        dim3 gg(M / 128, (N + 127) / 128);
        k_gemm_mfma<<<gg, 256, 0, stream>>>(A, Wt, featb, al_, ar_, el, er, N, K, M);
    } else {
        k_gemm_mfma64<<<(N + 255) / 256, 256, 0, stream>>>(A, Wt, featb, al_, ar_, el, er, N, K);
    }

    if (H == 4)
        k_node_msw<4><<<(N + 3) / 4, 256, 0, stream>>>(row_start, src_sorted, el, er, w, wb, s, N, E);
    else
        k_node_msw<1><<<(N + 3) / 4, 256, 0, stream>>>(row_start, src_sorted, el, er, w, wb, s, N, E);

    int G = 256 / (M / 8);
    if (outBf)
        k_agg_b<1><<<(N + G - 1) / G, 256, 0, stream>>>(row_start, src_sorted,
                                                        (const uint4*)featb, wb, s,
                                                        b_, rstOut, H, N, E, do_relu ? 1 : 0);
    else
        k_agg_b<0><<<(N + G - 1) / G, 256, 0, stream>>>(row_start, src_sorted,
                                                        (const uint4*)featb, wb, s,
                                                        b_, rstOut, H, N, E, do_relu ? 1 : 0);
}

extern "C" void kernel_launch(void* const* d_in, const int* in_sizes, int n_in,
                              void* d_out, int out_size, void* d_ws, size_t ws_size,
                              hipStream_t stream) {
    const float* features = (const float*)d_in[0];
    const int*   src = (const int*)d_in[1];
    const int*   dst = (const int*)d_in[2];
    const float* W1  = (const float*)d_in[3];
    const float* al1 = (const float*)d_in[4];
    const float* ar1 = (const float*)d_in[5];
    const float* b1  = (const float*)d_in[6];
    const float* W2  = (const float*)d_in[7];
    const float* al2 = (const float*)d_in[8];
    const float* ar2 = (const float*)d_in[9];
    const float* b2  = (const float*)d_in[10];
    const float* W3  = (const float*)d_in[11];
    const float* al3 = (const float*)d_in[12];
    const float* ar3 = (const float*)d_in[13];
    const float* b3  = (const float*)d_in[14];

    const int N = in_sizes[0] / 128;   // 50000
    const int E = in_sizes[1];         // 800000
    const int B = (N + 255) >> 8;      // buckets (196)
    const int n4 = N * 128 / 4;        // convert chunks

    float* ws   = (float*)d_ws;
    float* el   = ws;                        // [N,4]
    float* er   = el + (size_t)N * 4;        // [N,4]
    float* s    = er + (size_t)N * 4;        // [N,4]
    float* w    = s  + (size_t)N * 4;        // [H][E] fp32 logits (h-major)
    unsigned short* wb = (unsigned short*)(w + (size_t)E * 4);  // [H][E] bf16 weights
    int* row_start  = (int*)(wb + (size_t)E * 4);  // [N+1]
    int* src_sorted = row_start + N + 1;            // [E]
    int* ebuf       = src_sorted + E;               // [E]
    int* bcnt       = ebuf + E;                     // [256]
    int* bbase      = bcnt + 256;                   // [B+1]
    int* bcur       = bbase + 257;                  // [256]
    uintptr_t wp = (uintptr_t)(bcur + 256);
    wp = (wp + 15) & ~(uintptr_t)15;
    unsigned short* Wt1   = (unsigned short*)wp;       // [256*128]
    unsigned short* Wt2   = Wt1 + 32768;               // [256*256]
    unsigned short* Wt3   = Wt2 + 65536;               // [64*256]
    unsigned short* fconv = Wt3 + 16384;               // [N,128] bf16 features
    unsigned short* featb = fconv + (size_t)N * 128;   // [N,256] GEMM out
    unsigned short* rstb  = featb + (size_t)N * 256;   // [N,256] agg out (layers 1-2)

    // ---- fused prep: convert + weight transpose + bucket-counter zero ----
    int prep_total = n4 + 114688 + 256;
    k_prep<<<(prep_total + 255) / 256, 256, 0, stream>>>(features, fconv, n4,
                                                         W1, W2, W3, Wt1, Wt2, Wt3, bcnt);

    // ---- bucketed CSR build (coherence-friendly) ----
    int nbb = (E + NEB - 1) / NEB;
    k_bin_count<<<nbb, 256, 0, stream>>>(dst, bcnt, E, N);
    k_bucket_scan<<<1, 256, 0, stream>>>(bcnt, bbase, bcur, row_start + N, B, E);
    k_bin_scatter<<<nbb, 256, 0, stream>>>(dst, bcur, ebuf, E, N);
    k_csr_build<<<B, 256, 0, stream>>>(ebuf, src, bbase, row_start, src_sorted, N);

    // layer 1: A=fconv[N,128] -> featb[N,256] (+el/er fused) -> rstb bf16 (+relu)
    run_layer(fconv, 128, Wt1, al1, ar1, b1, 4, featb, rstb, true,
              el, er, w, wb, s, row_start, src_sorted, N, E, true, stream);
    // layer 2
    run_layer(rstb, 256, Wt2, al2, ar2, b2, 4, featb, rstb, true,
              el, er, w, wb, s, row_start, src_sorted, N, E, true, stream);
    // layer 3: H=1 -> d_out fp32 (mean over 1 head = id)
    run_layer(rstb, 256, Wt3, al3, ar3, b3, 1, featb, d_out, false,
              el, er, w, wb, s, row_start, src_sorted, N, E, false, stream);
}

// Round 20
// 422.478 us; speedup vs baseline: 1.1776x; 1.0163x over previous
//
#include <hip/hip_runtime.h>
#include <hip/hip_bf16.h>

#define LEAKY 0.2f

typedef __attribute__((ext_vector_type(8))) short short8;
typedef __attribute__((ext_vector_type(4))) float f32x4;

// round-to-nearest-even float -> bf16 bits (finite inputs)
__device__ inline unsigned short f2b(float f) {
    unsigned u = __float_as_uint(f);
    u += 0x7FFFu + ((u >> 16) & 1u);
    return (unsigned short)(u >> 16);
}
__device__ inline float b2f(unsigned short s) {
    return __uint_as_float(((unsigned)s) << 16);
}

// ---------------- fused prep: features->bf16, W->Wt bf16, bcnt=0 ----------------

__global__ void k_prep(const float* __restrict__ features, unsigned short* __restrict__ fconv,
                       int n4,
                       const float* __restrict__ W1, const float* __restrict__ W2,
                       const float* __restrict__ W3, unsigned short* __restrict__ Wt1,
                       unsigned short* __restrict__ Wt2, unsigned short* __restrict__ Wt3,
                       int* __restrict__ bcnt) {
    int idx = blockIdx.x * blockDim.x + threadIdx.x;
    if (idx < n4) {
        float4 v = *(const float4*)(features + idx * 4);
        ushort4 o;
        o.x = f2b(v.x); o.y = f2b(v.y); o.z = f2b(v.z); o.w = f2b(v.w);
        *(ushort4*)(fconv + idx * 4) = o;
        return;
    }
    int j = idx - n4;
    if (j < 32768) {                       // L1: K=128, M=256
        int m = j >> 7, k = j & 127;
        Wt1[j] = f2b(W1[(size_t)k * 256 + m]);
        return;
    }
    if (j < 98304) {                       // L2: K=256, M=256
        int jj = j - 32768;
        int m = jj >> 8, k = jj & 255;
        Wt2[jj] = f2b(W2[(size_t)k * 256 + m]);
        return;
    }
    if (j < 114688) {                      // L3: K=256, M=64
        int jj = j - 98304;
        int m = jj >> 8, k = jj & 255;
        Wt3[jj] = f2b(W3[(size_t)k * 64 + m]);
        return;
    }
    int z = j - 114688;
    if (z < 256) bcnt[z] = 0;
}

// ---------------- bucketed CSR build ----------------
// bucket k = dst >> 8 (256 nodes/bucket). Avoids cross-XCD cache-line
// bouncing: per-bucket output regions are written by single blocks.

#define NEB 8192   // edges per binning block

__global__ __launch_bounds__(256)
void k_bin_count(const int* __restrict__ dst, int* __restrict__ bcnt, int E, int N) {
    __shared__ int lc[256];
    const int tid = threadIdx.x;
    lc[tid] = 0;
    __syncthreads();
    const int b0 = blockIdx.x * NEB;
    const int cnt = min(NEB, E - b0);
    for (int j = 0; j < NEB / 256; ++j) {
        int idx = j * 256 + tid;
        if (idx < cnt) {
            int dn = dst[b0 + idx];
            if ((unsigned)dn < (unsigned)N) atomicAdd(&lc[dn >> 8], 1);
        }
    }
    __syncthreads();
    if (lc[tid] > 0) atomicAdd(&bcnt[tid], lc[tid]);
}

__global__ __launch_bounds__(256)
void k_bucket_scan(const int* __restrict__ bcnt, int* __restrict__ bbase,
                   int* __restrict__ bcur, int* __restrict__ row_start_N, int B, int E) {
    __shared__ int ws[4];
    const int tid = threadIdx.x, lane = tid & 63, wave = tid >> 6;
    int v = (tid < B) ? bcnt[tid] : 0;
    int x = v;
    #pragma unroll
    for (int off = 1; off < 64; off <<= 1) {
        int t = __shfl_up(x, off, 64);
        if (lane >= off) x += t;
    }
    if (lane == 63) ws[wave] = x;
    __syncthreads();
    if (tid == 0) {
        int c = 0;
        #pragma unroll
        for (int wv = 0; wv < 4; ++wv) { int t = ws[wv]; ws[wv] = c; c += t; }
    }
    __syncthreads();
    int excl = x - v + ws[wave];
    if (tid < B) { bbase[tid] = excl; bcur[tid] = excl; }
    if (tid == 0) { bbase[B] = E; *row_start_N = E; }
}

// bin edges into bucket-contiguous ebuf; entry packs (dst&255)<<24 | e.
__global__ __launch_bounds__(256)
void k_bin_scatter(const int* __restrict__ dst, int* __restrict__ bcur,
                   int* __restrict__ ebuf, int E, int N) {
    __shared__ int lc[256], lofs[256], lcur[256], gres[256];
    __shared__ int stage_e[NEB];
    __shared__ unsigned short stage_d[NEB];
    __shared__ int ws[4];
    const int tid = threadIdx.x, lane = tid & 63, wave = tid >> 6;
    const int b0 = blockIdx.x * NEB;
    const int cnt = min(NEB, E - b0);
    lc[tid] = 0;
    __syncthreads();

    int dreg[NEB / 256];
    #pragma unroll
    for (int j = 0; j < NEB / 256; ++j) {
        int idx = j * 256 + tid;
        dreg[j] = -1;
        if (idx < cnt) {
            int dn = dst[b0 + idx];
            if ((unsigned)dn < (unsigned)N) {
                dreg[j] = dn;
                atomicAdd(&lc[dn >> 8], 1);
            }
        }
    }
    __syncthreads();
    {
        int v = lc[tid];
        int x = v;
        #pragma unroll
        for (int off = 1; off < 64; off <<= 1) {
            int t = __shfl_up(x, off, 64);
            if (lane >= off) x += t;
        }
        if (lane == 63) ws[wave] = x;
        __syncthreads();
        if (tid == 0) {
            int c = 0;
            #pragma unroll
            for (int wv = 0; wv < 4; ++wv) { int t = ws[wv]; ws[wv] = c; c += t; }
        }
        __syncthreads();
        int excl = x - v + ws[wave];
        lofs[tid] = excl;
        lcur[tid] = excl;
    }
    __syncthreads();
    #pragma unroll
    for (int j = 0; j < NEB / 256; ++j) {
        int dn = dreg[j];
        if (dn >= 0) {
            int p = atomicAdd(&lcur[dn >> 8], 1);
            stage_e[p] = b0 + j * 256 + tid;
            stage_d[p] = (unsigned short)dn;
        }
    }
    __syncthreads();
    if (lc[tid] > 0) gres[tid] = atomicAdd(&bcur[tid], lc[tid]);
    __syncthreads();
    int total = lcur[255];
    for (int i = tid; i < total; i += 256) {
        int dn = stage_d[i];
        int k = dn >> 8;
        int dest = gres[k] + (i - lofs[k]);
        ebuf[dest] = ((dn & 255) << 24) | stage_e[i];
    }
}

// per bucket: derive row_start for its 256 nodes and write src_sorted region.
__global__ __launch_bounds__(256)
void k_csr_build(const int* __restrict__ ebuf, const int* __restrict__ src,
                 const int* __restrict__ bbase, int* __restrict__ row_start,
                 int* __restrict__ src_sorted, int N) {
    __shared__ int lc[256], lcur[256];
    __shared__ int ws[4];
    const int tid = threadIdx.x, lane = tid & 63, wave = tid >> 6;
    const int k = blockIdx.x;
    const int base = k << 8;
    const int e0 = bbase[k];
    const int cnt = bbase[k + 1] - e0;
    lc[tid] = 0;
    __syncthreads();
    for (int i = tid; i < cnt; i += 256) {
        int rel = ((unsigned)ebuf[e0 + i]) >> 24;
        atomicAdd(&lc[rel], 1);
    }
    __syncthreads();
    {
        int v = lc[tid];
        int x = v;
        #pragma unroll
        for (int off = 1; off < 64; off <<= 1) {
            int t = __shfl_up(x, off, 64);
            if (lane >= off) x += t;
        }
        if (lane == 63) ws[wave] = x;
        __syncthreads();
        if (tid == 0) {
            int c = 0;
            #pragma unroll
            for (int wv = 0; wv < 4; ++wv) { int t = ws[wv]; ws[wv] = c; c += t; }
        }
        __syncthreads();
        int excl = x - v + ws[wave];
        lcur[tid] = excl;
        int n = base + tid;
        if (n < N) row_start[n] = e0 + excl;
    }
    __syncthreads();
    for (int i = tid; i < cnt; i += 256) {
        int val = ebuf[e0 + i];
        int rel = ((unsigned)val) >> 24;
        int e = val & 0xFFFFFF;
        int p = atomicAdd(&lcur[rel], 1);
        src_sorted[e0 + p] = src[e];
    }
}

// ---------------- MFMA GEMM (BN=128) + fused el/er epilogue ----------------

__global__ __launch_bounds__(256)
void k_gemm_mfma(const unsigned short* __restrict__ A, const unsigned short* __restrict__ Wt,
                 unsigned short* __restrict__ Cb, const float* __restrict__ al,
                 const float* __restrict__ ar, float* __restrict__ el,
                 float* __restrict__ er, int N, int K, int M) {
    constexpr int STR = 40;
    __shared__ unsigned short As[128 * STR];
    __shared__ unsigned short Bs[128 * STR];
    const int tid  = threadIdx.x;
    const int wave = tid >> 6;
    const int lane = tid & 63;
    const int row0 = blockIdx.y * 128;
    const int col0 = blockIdx.x * 128;
    const int wr = (wave >> 1) * 64;
    const int wc = (wave & 1) * 64;
    const int m16 = lane & 15;
    const int q   = lane >> 4;

    const int s_row = tid >> 1;
    const int s_off = (tid & 1) * 16;

    f32x4 acc[4][4] = {};

    for (int k0 = 0; k0 < K; k0 += 32) {
        {
            int gr = row0 + s_row;
            short8 z = {};
            short8 v0 = z, v1 = z;
            if (gr < N) {
                const unsigned short* ap = A + (size_t)gr * K + k0 + s_off;
                v0 = *(const short8*)ap;
                v1 = *(const short8*)(ap + 8);
            }
            *(short8*)&As[s_row * STR + s_off]     = v0;
            *(short8*)&As[s_row * STR + s_off + 8] = v1;
        }
        {
            const unsigned short* sp = Wt + (size_t)(col0 + s_row) * K + k0 + s_off;
            *(short8*)&Bs[s_row * STR + s_off]     = *(const short8*)sp;
            *(short8*)&Bs[s_row * STR + s_off + 8] = *(const short8*)(sp + 8);
        }
        __syncthreads();

        short8 afr[4], bfr[4];
        #pragma unroll
        for (int rg = 0; rg < 4; ++rg)
            afr[rg] = *(const short8*)&As[(wr + rg * 16 + m16) * STR + q * 8];
        #pragma unroll
        for (int cg = 0; cg < 4; ++cg)
            bfr[cg] = *(const short8*)&Bs[(wc + cg * 16 + m16) * STR + q * 8];
        #pragma unroll
        for (int rg = 0; rg < 4; ++rg)
            #pragma unroll
            for (int cg = 0; cg < 4; ++cg)
                acc[rg][cg] = __builtin_amdgcn_mfma_f32_16x16x32_bf16(
                    afr[rg], bfr[cg], acc[rg][cg], 0, 0, 0);
        __syncthreads();
    }

    const int H = M >> 6;
    const int h = (col0 + wc) >> 6;
    float alv[4], arv[4];
    #pragma unroll
    for (int cg = 0; cg < 4; ++cg) {
        alv[cg] = al[h * 64 + cg * 16 + m16];
        arv[cg] = ar[h * 64 + cg * 16 + m16];
    }

    #pragma unroll
    for (int rg = 0; rg < 4; ++rg) {
        #pragma unroll
        for (int r = 0; r < 4; ++r) {
            int gr = row0 + wr + rg * 16 + q * 4 + r;
            float pl = 0.f, pr = 0.f;
            #pragma unroll
            for (int cg = 0; cg < 4; ++cg) {
                pl = fmaf(acc[rg][cg][r], alv[cg], pl);
                pr = fmaf(acc[rg][cg][r], arv[cg], pr);
            }
            #pragma unroll
            for (int off = 1; off < 16; off <<= 1) {
                pl += __shfl_xor(pl, off, 64);
                pr += __shfl_xor(pr, off, 64);
            }
            if (gr < N) {
                unsigned short* bp = Cb + (size_t)gr * M + col0 + wc + m16;
                #pragma unroll
                for (int cg = 0; cg < 4; ++cg)
                    bp[cg * 16] = f2b(acc[rg][cg][r]);
                if (m16 == 0) {
                    el[gr * H + h] = pl;
                    er[gr * H + h] = pr;
                }
            }
        }
    }
}

// ---------------- MFMA GEMM (M=64): 256x64 tile + fused el/er (H=1) ----------

__global__ __launch_bounds__(256)
void k_gemm_mfma64(const unsigned short* __restrict__ A, const unsigned short* __restrict__ Wt,
                   unsigned short* __restrict__ Cb, const float* __restrict__ al,
                   const float* __restrict__ ar, float* __restrict__ el,
                   float* __restrict__ er, int N, int K) {
    constexpr int M = 64;
    constexpr int STR = 40;
    __shared__ unsigned short As[256 * STR];
    __shared__ unsigned short Bs[64 * STR];
    const int tid  = threadIdx.x;
    const int wave = tid >> 6;
    const int lane = tid & 63;
    const int row0 = blockIdx.x * 256;
    const int wr = wave * 64;
    const int m16 = lane & 15;
    const int q   = lane >> 4;

    const int s_row = tid >> 1;
    const int s_off = (tid & 1) * 16;
    const int b_row = tid >> 2;
    const int b_chk = (tid & 3) * 8;

    f32x4 acc[4][4] = {};

    for (int k0 = 0; k0 < K; k0 += 32) {
        #pragma unroll
        for (int p = 0; p < 2; ++p) {
            int r = s_row + p * 128;
            int gr = row0 + r;
            short8 z = {};
            short8 v0 = z, v1 = z;
            if (gr < N) {
                const unsigned short* ap = A + (size_t)gr * K + k0 + s_off;
                v0 = *(const short8*)ap;
                v1 = *(const short8*)(ap + 8);
            }
            *(short8*)&As[r * STR + s_off]     = v0;
            *(short8*)&As[r * STR + s_off + 8] = v1;
        }
        {
            const unsigned short* sp = Wt + (size_t)b_row * K + k0 + b_chk;
            *(short8*)&Bs[b_row * STR + b_chk] = *(const short8*)sp;
        }
        __syncthreads();

        short8 afr[4], bfr[4];
        #pragma unroll
        for (int rg = 0; rg < 4; ++rg)
            afr[rg] = *(const short8*)&As[(wr + rg * 16 + m16) * STR + q * 8];
        #pragma unroll
        for (int cg = 0; cg < 4; ++cg)
            bfr[cg] = *(const short8*)&Bs[(cg * 16 + m16) * STR + q * 8];
        #pragma unroll
        for (int rg = 0; rg < 4; ++rg)
            #pragma unroll
            for (int cg = 0; cg < 4; ++cg)
                acc[rg][cg] = __builtin_amdgcn_mfma_f32_16x16x32_bf16(
                    afr[rg], bfr[cg], acc[rg][cg], 0, 0, 0);
        __syncthreads();
    }

    float alv[4], arv[4];
    #pragma unroll
    for (int cg = 0; cg < 4; ++cg) {
        alv[cg] = al[cg * 16 + m16];
        arv[cg] = ar[cg * 16 + m16];
    }

    #pragma unroll
    for (int rg = 0; rg < 4; ++rg) {
        #pragma unroll
        for (int r = 0; r < 4; ++r) {
            int gr = row0 + wr + rg * 16 + q * 4 + r;
            float pl = 0.f, pr = 0.f;
            #pragma unroll
            for (int cg = 0; cg < 4; ++cg) {
                pl = fmaf(acc[rg][cg][r], alv[cg], pl);
                pr = fmaf(acc[rg][cg][r], arv[cg], pr);
            }
            #pragma unroll
            for (int off = 1; off < 16; off <<= 1) {
                pl += __shfl_xor(pl, off, 64);
                pr += __shfl_xor(pr, off, 64);
            }
            if (gr < N) {
                unsigned short* bp = Cb + (size_t)gr * M + m16;
                #pragma unroll
                for (int cg = 0; cg < 4; ++cg)
                    bp[cg * 16] = f2b(acc[rg][cg][r]);
                if (m16 == 0) {
                    el[gr] = pl;
                    er[gr] = pr;
                }
            }
        }
    }
}

// ---------------- attention pieces (CSR, atomic-free) ----------------

// softmax per node: one wave per node; logits held in LDS (CAP slots,
// bank-staggered) instead of a global fp32 round-trip; deg>CAP spills to
// global w (never hit for this graph; correct if hit). bf16 exp-weights
// wb[h*E+i] for the agg; s = 1/sum. No barriers: each wave's LDS region
// is private and each lane reads only its own slots.
template<int H>
__global__ __launch_bounds__(256)
void k_node_msw(const int* __restrict__ row_start, const int* __restrict__ src_sorted,
                const float* __restrict__ el, const float* __restrict__ er,
                float* __restrict__ w, unsigned short* __restrict__ wb,
                float* __restrict__ s, int N, int E) {
    constexpr int STRIDE = 64 / H;
    constexpr int CAP = 64;
    constexpr int LSTR = 65;
    __shared__ float ldsw[4 * H * LSTR];
    const int wv = threadIdx.x >> 6;
    const int n = blockIdx.x * 4 + wv;
    if (n >= N) return;
    const int lane = threadIdx.x & 63;
    const int eo = lane / H;
    const int h  = lane % H;
    float* lw = &ldsw[(wv * H + h) * LSTR];
    float erv = er[n * H + h];
    int b0 = row_start[n], b1 = row_start[n + 1];
    float mx = -INFINITY;
    for (int i = b0 + eo; i < b1; i += STRIDE) {
        float x = el[src_sorted[i] * H + h] + erv;
        x = (x > 0.f) ? x : LEAKY * x;
        int j = i - b0;
        if (j < CAP) lw[j] = x;
        else w[(size_t)h * E + i] = x;
        mx = fmaxf(mx, x);
    }
    #pragma unroll
    for (int off = H; off < 64; off <<= 1)
        mx = fmaxf(mx, __shfl_xor(mx, off, 64));
    float sum = 0.f;
    for (int i = b0 + eo; i < b1; i += STRIDE) {
        int j = i - b0;
        float x = (j < CAP) ? lw[j] : w[(size_t)h * E + i];
        float e = __expf(x - mx);
        sum += e;
        wb[(size_t)h * E + i] = f2b(e);
    }
    #pragma unroll
    for (int off = H; off < 64; off <<= 1)
        sum += __shfl_xor(sum, off, 64);
    if (lane < H) s[n * H + lane] = 1.0f / fmaxf(sum, 1e-30f);
}

// Aggregation, packed bf16 octets (uint4 = 8 bf16/edge/thread), depth-8;
// bf16 weights, 1/sum+bias epilogue.
template<int OUTBF>
__global__ __launch_bounds__(256)
void k_agg_b(const int* __restrict__ row_start, const int* __restrict__ src_sorted,
             const uint4* __restrict__ featp, const unsigned short* __restrict__ wb,
             const float* __restrict__ s, const float* __restrict__ bias,
             void* __restrict__ outv, int H, int N, int E, int do_relu) {
    const int M = H * 64;
    const int P = M >> 3;
    const int G = 256 / P;
    const int grp = threadIdx.x / P;
    const int t = threadIdx.x - grp * P;
    const int n = blockIdx.x * G + grp;
    if (n >= N) return;
    const int d0 = t * 8;
    const int h = d0 >> 6;
    const unsigned short* wh = wb + (size_t)h * E;

    float a[8] = {};
    int b0 = row_start[n], b1 = row_start[n + 1];
    int i = b0;
    for (; i + 8 <= b1; i += 8) {
        int ss[8]; float wv[8]; uint4 pv[8];
        #pragma unroll
        for (int j = 0; j < 8; ++j) ss[j] = src_sorted[i + j];
        #pragma unroll
        for (int j = 0; j < 8; ++j) wv[j] = b2f(wh[i + j]);
        #pragma unroll
        for (int j = 0; j < 8; ++j) pv[j] = featp[(size_t)ss[j] * P + t];
        #pragma unroll
        for (int j = 0; j < 8; ++j) {
            a[0] = fmaf(__uint_as_float(pv[j].x << 16),         wv[j], a[0]);
            a[1] = fmaf(__uint_as_float(pv[j].x & 0xFFFF0000u), wv[j], a[1]);
            a[2] = fmaf(__uint_as_float(pv[j].y << 16),         wv[j], a[2]);
            a[3] = fmaf(__uint_as_float(pv[j].y & 0xFFFF0000u), wv[j], a[3]);
            a[4] = fmaf(__uint_as_float(pv[j].z << 16),         wv[j], a[4]);
            a[5] = fmaf(__uint_as_float(pv[j].z & 0xFFFF0000u), wv[j], a[5]);
            a[6] = fmaf(__uint_as_float(pv[j].w << 16),         wv[j], a[6]);
            a[7] = fmaf(__uint_as_float(pv[j].w & 0xFFFF0000u), wv[j], a[7]);
        }
    }
    for (; i + 4 <= b1; i += 4) {
        int ss[4]; float wv[4]; uint4 pv[4];
        #pragma unroll
        for (int j = 0; j < 4; ++j) ss[j] = src_sorted[i + j];
        #pragma unroll
        for (int j = 0; j < 4; ++j) wv[j] = b2f(wh[i + j]);
        #pragma unroll
        for (int j = 0; j < 4; ++j) pv[j] = featp[(size_t)ss[j] * P + t];
        #pragma unroll
        for (int j = 0; j < 4; ++j) {
            a[0] = fmaf(__uint_as_float(pv[j].x << 16),         wv[j], a[0]);
            a[1] = fmaf(__uint_as_float(pv[j].x & 0xFFFF0000u), wv[j], a[1]);
            a[2] = fmaf(__uint_as_float(pv[j].y << 16),         wv[j], a[2]);
            a[3] = fmaf(__uint_as_float(pv[j].y & 0xFFFF0000u), wv[j], a[3]);
            a[4] = fmaf(__uint_as_float(pv[j].z << 16),         wv[j], a[4]);
            a[5] = fmaf(__uint_as_float(pv[j].z & 0xFFFF0000u), wv[j], a[5]);
            a[6] = fmaf(__uint_as_float(pv[j].w << 16),         wv[j], a[6]);
            a[7] = fmaf(__uint_as_float(pv[j].w & 0xFFFF0000u), wv[j], a[7]);
        }
    }
    for (; i < b1; ++i) {
        uint4 pv = featp[(size_t)src_sorted[i] * P + t];
        float wv = b2f(wh[i]);
        a[0] = fmaf(__uint_as_float(pv.x << 16),         wv, a[0]);
        a[1] = fmaf(__uint_as_float(pv.x & 0xFFFF0000u), wv, a[1]);
        a[2] = fmaf(__uint_as_float(pv.y << 16),         wv, a[2]);
        a[3] = fmaf(__uint_as_float(pv.y & 0xFFFF0000u), wv, a[3]);
        a[4] = fmaf(__uint_as_float(pv.z << 16),         wv, a[4]);
        a[5] = fmaf(__uint_as_float(pv.z & 0xFFFF0000u), wv, a[5]);
        a[6] = fmaf(__uint_as_float(pv.w << 16),         wv, a[6]);
        a[7] = fmaf(__uint_as_float(pv.w & 0xFFFF0000u), wv, a[7]);
    }
    float rs = s[n * H + h];
    float4 bv0 = *(const float4*)(bias + d0);
    float4 bv1 = *(const float4*)(bias + d0 + 4);
    a[0] = fmaf(a[0], rs, bv0.x); a[1] = fmaf(a[1], rs, bv0.y);
    a[2] = fmaf(a[2], rs, bv0.z); a[3] = fmaf(a[3], rs, bv0.w);
    a[4] = fmaf(a[4], rs, bv1.x); a[5] = fmaf(a[5], rs, bv1.y);
    a[6] = fmaf(a[6], rs, bv1.z); a[7] = fmaf(a[7], rs, bv1.w);
    if (do_relu) {
        #pragma unroll
        for (int j = 0; j < 8; ++j) a[j] = fmaxf(a[j], 0.f);
    }
    if (OUTBF) {
        uint4 o;
        o.x = (unsigned)f2b(a[0]) | ((unsigned)f2b(a[1]) << 16);
        o.y = (unsigned)f2b(a[2]) | ((unsigned)f2b(a[3]) << 16);
        o.z = (unsigned)f2b(a[4]) | ((unsigned)f2b(a[5]) << 16);
        o.w = (unsigned)f2b(a[6]) | ((unsigned)f2b(a[7]) << 16);
        *(uint4*)((unsigned short*)outv + (size_t)n * M + d0) = o;
    } else {
        *(float4*)((float*)outv + (size_t)n * M + d0)     = make_float4(a[0], a[1], a[2], a[3]);
        *(float4*)((float*)outv + (size_t)n * M + d0 + 4) = make_float4(a[4], a[5], a[6], a[7]);
    }
}

// ---------------- host side ----------------

static void run_layer(const unsigned short* A, int K, const unsigned short* Wt,
                      const float* al_, const float* ar_, const float* b_, int H,
                      unsigned short* featb, void* rstOut, bool outBf,
                      float* el, float* er, float* w, unsigned short* wb, float* s,
                      const int* row_start, const int* src_sorted,
                      int N, int E, bool do_relu, hipStream_t stream) {
    const int M = H * 64;
    if (M % 128 == 0) {
        dim3 gg(M / 128, (N + 127) / 128);
        k_gemm_mfma<<<gg, 256, 0, stream>>>(A, Wt, featb, al_, ar_, el, er, N, K, M);
    } else {
        k_gemm_mfma64<<<(N + 255) / 256, 256, 0, stream>>>(A, Wt, featb, al_, ar_, el, er, N, K);
    }

    if (H == 4)
        k_node_msw<4><<<(N + 3) / 4, 256, 0, stream>>>(row_start, src_sorted, el, er, w, wb, s, N, E);
    else
        k_node_msw<1><<<(N + 3) / 4, 256, 0, stream>>>(row_start, src_sorted, el, er, w, wb, s, N, E);

    int G = 256 / (M / 8);
    if (outBf)
        k_agg_b<1><<<(N + G - 1) / G, 256, 0, stream>>>(row_start, src_sorted,
                                                        (const uint4*)featb, wb, s,
                                                        b_, rstOut, H, N, E, do_relu ? 1 : 0);
    else
        k_agg_b<0><<<(N + G - 1) / G, 256, 0, stream>>>(row_start, src_sorted,
                                                        (const uint4*)featb, wb, s,
                                                        b_, rstOut, H, N, E, do_relu ? 1 : 0);
}

extern "C" void kernel_launch(void* const* d_in, const int* in_sizes, int n_in,
                              void* d_out, int out_size, void* d_ws, size_t ws_size,
                              hipStream_t stream) {
    const float* features = (const float*)d_in[0];
    const int*   src = (const int*)d_in[1];
    const int*   dst = (const int*)d_in[2];
    const float* W1  = (const float*)d_in[3];
    const float* al1 = (const float*)d_in[4];
    const float* ar1 = (const float*)d_in[5];
    const float* b1  = (const float*)d_in[6];
    const float* W2  = (const float*)d_in[7];
    const float* al2 = (const float*)d_in[8];
    const float* ar2 = (const float*)d_in[9];
    const float* b2  = (const float*)d_in[10];
    const float* W3  = (const float*)d_in[11];
    const float* al3 = (const float*)d_in[12];
    const float* ar3 = (const float*)d_in[13];
    const float* b3  = (const float*)d_in[14];

    const int N = in_sizes[0] / 128;   // 50000
    const int E = in_sizes[1];         // 800000
    const int B = (N + 255) >> 8;      // buckets (196)
    const int n4 = N * 128 / 4;        // convert chunks

    float* ws   = (float*)d_ws;
    float* el   = ws;                        // [N,4]
    float* er   = el + (size_t)N * 4;        // [N,4]
    float* s    = er + (size_t)N * 4;        // [N,4]
    float* w    = s  + (size_t)N * 4;        // [H][E] fp32 spill (deg>64 only)
    unsigned short* wb = (unsigned short*)(w + (size_t)E * 4);  // [H][E] bf16 weights
    int* row_start  = (int*)(wb + (size_t)E * 4);  // [N+1]
    int* src_sorted = row_start + N + 1;            // [E]
    int* ebuf       = src_sorted + E;               // [E]
    int* bcnt       = ebuf + E;                     // [256]
    int* bbase      = bcnt + 256;                   // [B+1]
    int* bcur       = bbase + 257;                  // [256]
    uintptr_t wp = (uintptr_t)(bcur + 256);
    wp = (wp + 15) & ~(uintptr_t)15;
    unsigned short* Wt1   = (unsigned short*)wp;       // [256*128]
    unsigned short* Wt2   = Wt1 + 32768;               // [256*256]
    unsigned short* Wt3   = Wt2 + 65536;               // [64*256]
    unsigned short* fconv = Wt3 + 16384;               // [N,128] bf16 features
    unsigned short* featb = fconv + (size_t)N * 128;   // [N,256] GEMM out
    unsigned short* rstb  = featb + (size_t)N * 256;   // [N,256] agg out (layers 1-2)

    // ---- fused prep: convert + weight transpose + bucket-counter zero ----
    int prep_total = n4 + 114688 + 256;
    k_prep<<<(prep_total + 255) / 256, 256, 0, stream>>>(features, fconv, n4,
                                                         W1, W2, W3, Wt1, Wt2, Wt3, bcnt);

    // ---- bucketed CSR build (coherence-friendly) ----
    int nbb = (E + NEB - 1) / NEB;
    k_bin_count<<<nbb, 256, 0, stream>>>(dst, bcnt, E, N);
    k_bucket_scan<<<1, 256, 0, stream>>>(bcnt, bbase, bcur, row_start + N, B, E);
    k_bin_scatter<<<nbb, 256, 0, stream>>>(dst, bcur, ebuf, E, N);
    k_csr_build<<<B, 256, 0, stream>>>(ebuf, src, bbase, row_start, src_sorted, N);

    // layer 1: A=fconv[N,128] -> featb[N,256] (+el/er fused) -> rstb bf16 (+relu)
    run_layer(fconv, 128, Wt1, al1, ar1, b1, 4, featb, rstb, true,
              el, er, w, wb, s, row_start, src_sorted, N, E, true, stream);
    // layer 2
    run_layer(rstb, 256, Wt2, al2, ar2, b2, 4, featb, rstb, true,
              el, er, w, wb, s, row_start, src_sorted, N, E, true, stream);
    // layer 3: H=1 -> d_out fp32 (mean over 1 head = id)
    run_layer(rstb, 256, Wt3, al3, ar3, b3, 1, featb, d_out, false,
              el, er, w, wb, s, row_start, src_sorted, N, E, false, stream);
}